// Round 4
// baseline (846.110 us; speedup 1.0000x reference)
//
#include <hip/hip_runtime.h>

#define N_NODES 50000
#define N_EDGES 800000
#define N_META 3
#define IN_DIM 256
#define HD 128
#define HEADS 8
#define HID 16
#define OUT_DIM 8

using bf16x8 = __attribute__((ext_vector_type(8))) short;
using f32x4  = __attribute__((ext_vector_type(4))) float;

__device__ __forceinline__ float bf2f(unsigned short u) {
  union { unsigned int i; float f; } x; x.i = ((unsigned int)u) << 16; return x.f;
}
__device__ __forceinline__ unsigned short f2bf(float f) {
  union { float f; unsigned int i; } x; x.f = f;
  unsigned int r = x.i + 0x7fffu + ((x.i >> 16) & 1u);
  return (unsigned short)(r >> 16);
}
__device__ __forceinline__ unsigned int encf(float f) {
  unsigned int u = __float_as_uint(f);
  return (u & 0x80000000u) ? ~u : (u | 0x80000000u);
}
__device__ __forceinline__ float decf(unsigned int u) {
  return (u & 0x80000000u) ? __uint_as_float(u & 0x7fffffffu) : __uint_as_float(~u);
}

// ---------------- prep: fcw -> fcwT bf16 [M][128][256]; w1 -> w1T bf16 [128][128]
__global__ __launch_bounds__(256)
void prep_kernel(const float* __restrict__ fcw, const float* __restrict__ w1,
                 unsigned short* __restrict__ fcwT, unsigned short* __restrict__ w1T) {
  int i = blockIdx.x * 256 + threadIdx.x;
  const int NFC = N_META * IN_DIM * HD;
  if (i < NFC) {
    int p = i / (IN_DIM * HD);
    int rem = i - p * (IN_DIM * HD);
    int k = rem / HD, n = rem - k * HD;
    fcwT[(size_t)p * HD * IN_DIM + n * IN_DIM + k] = f2bf(fcw[i]);
  } else if (i < NFC + HD * HD) {
    int j = i - NFC;
    int k = j / HD, n = j - k * HD;
    w1T[n * HD + k] = f2bf(w1[j]);
  }
}

// ---------------- MFMA GEMM: featb = bf16(h @ fc_w[m])  ----------------------
__global__ __launch_bounds__(256)
void gemm_feat_mfma(const float* __restrict__ A,            // h [N,256] f32
                    const unsigned short* __restrict__ BT,  // fcwT [128][256] bf16
                    unsigned short* __restrict__ Cb,        // featb [N,128] bf16
                    int nrows) {
  __shared__ unsigned short As[64 * 40];
  __shared__ unsigned short Bs[128 * 40];
  int tid = threadIdx.x;
  int w = tid >> 6, l = tid & 63, q = l >> 4, s = l & 15;
  int row0 = blockIdx.x * 64;
  f32x4 acc[8] = {};
  for (int k0 = 0; k0 < IN_DIM; k0 += 32) {
    {
      int r = tid >> 2, c = (tid & 3) * 8;
      int gr = row0 + r;
      float4 a0, a1;
      if (gr < nrows) {
        a0 = *(const float4*)(A + (size_t)gr * IN_DIM + k0 + c);
        a1 = *(const float4*)(A + (size_t)gr * IN_DIM + k0 + c + 4);
      } else {
        a0 = make_float4(0.f, 0.f, 0.f, 0.f); a1 = a0;
      }
      ushort4 u0, u1;
      u0.x = f2bf(a0.x); u0.y = f2bf(a0.y); u0.z = f2bf(a0.z); u0.w = f2bf(a0.w);
      u1.x = f2bf(a1.x); u1.y = f2bf(a1.y); u1.z = f2bf(a1.z); u1.w = f2bf(a1.w);
      *(ushort4*)&As[r * 40 + c]     = u0;
      *(ushort4*)&As[r * 40 + c + 4] = u1;
    }
    {
      int n = tid >> 1, c = (tid & 1) * 16;
      uint4 b0 = *(const uint4*)(BT + (size_t)n * IN_DIM + k0 + c);
      uint4 b1 = *(const uint4*)(BT + (size_t)n * IN_DIM + k0 + c + 8);
      *(uint4*)&Bs[n * 40 + c]     = b0;
      *(uint4*)&Bs[n * 40 + c + 8] = b1;
    }
    __syncthreads();
    bf16x8 af = *(bf16x8*)&As[(w * 16 + s) * 40 + q * 8];
    #pragma unroll
    for (int f = 0; f < 8; ++f) {
      bf16x8 bf = *(bf16x8*)&Bs[(f * 16 + s) * 40 + q * 8];
      acc[f] = __builtin_amdgcn_mfma_f32_16x16x32_bf16(af, bf, acc[f], 0, 0, 0);
    }
    __syncthreads();
  }
  #pragma unroll
  for (int f = 0; f < 8; ++f) {
    #pragma unroll
    for (int r = 0; r < 4; ++r) {
      int gr = row0 + w * 16 + q * 4 + r;
      if (gr < nrows) Cb[(size_t)gr * HD + f * 16 + s] = f2bf(acc[f][r]);
    }
  }
}

// ---------------- el/er per (node, head), vectorized bf16 reads ---------------
__global__ __launch_bounds__(256)
void el_er_kernel(const unsigned short* __restrict__ feat,
                  const float* __restrict__ al, const float* __restrict__ ar,
                  float* __restrict__ el, float* __restrict__ er) {
  int i = blockIdx.x * blockDim.x + threadIdx.x;
  if (i >= N_NODES * HEADS) return;
  int node = i >> 3, hh = i & 7;
  const unsigned short* f = feat + (size_t)node * HD + hh * HID;
  uint4 u0 = *(const uint4*)(f);
  uint4 u1 = *(const uint4*)(f + 8);
  unsigned int uu[8] = {u0.x, u0.y, u0.z, u0.w, u1.x, u1.y, u1.z, u1.w};
  float sl = 0.f, sr = 0.f;
  #pragma unroll
  for (int p = 0; p < 8; ++p) {
    float v0 = __uint_as_float(uu[p] << 16);
    float v1 = __uint_as_float(uu[p] & 0xffff0000u);
    int d = p * 2;
    sl += v0 * al[hh * HID + d]     + v1 * al[hh * HID + d + 1];
    sr += v0 * ar[hh * HID + d]     + v1 * ar[hh * HID + d + 1];
  }
  el[i] = sl; er[i] = sr;
}

// ---------------- batched CSR build ------------------------------------------
__global__ __launch_bounds__(256)
void hist_kernel(const int* __restrict__ edges, int* __restrict__ cnt) {
  int p = blockIdx.y;
  int e = blockIdx.x * 256 + threadIdx.x;
  if (e < N_EDGES)
    atomicAdd(&cnt[p * N_NODES + edges[(size_t)p * 2 * N_EDGES + N_EDGES + e]], 1);
}

__global__ __launch_bounds__(1024)
void scan1_kernel(const int* __restrict__ cnt, int* __restrict__ bsum, int n) {
  __shared__ int ws[16];
  int tid = threadIdx.x, lane = tid & 63, wid = tid >> 6;
  int i = blockIdx.x * 1024 + tid;
  int v = (i < n) ? cnt[i] : 0;
  #pragma unroll
  for (int d = 32; d; d >>= 1) v += __shfl_xor(v, d);
  if (lane == 0) ws[wid] = v;
  __syncthreads();
  if (tid == 0) {
    int s = 0;
    #pragma unroll
    for (int k = 0; k < 16; ++k) s += ws[k];
    bsum[blockIdx.x] = s;
  }
}

__global__ __launch_bounds__(64)
void scan2_kernel(const int* __restrict__ bsum, int* __restrict__ bbase,
                  int* __restrict__ offs_end, int nb) {
  int lane = threadIdx.x;
  int carry = 0;
  for (int base = 0; base < nb; base += 64) {
    int i = base + lane;
    int v = (i < nb) ? bsum[i] : 0;
    int s = v;
    #pragma unroll
    for (int d = 1; d < 64; d <<= 1) {
      int t = __shfl_up(s, d);
      if (lane >= d) s += t;
    }
    if (i < nb) bbase[i] = carry + s - v;
    carry += __shfl(s, 63);
  }
  if (lane == 0) *offs_end = carry;
}

__global__ __launch_bounds__(1024)
void scan3_kernel(const int* __restrict__ cnt, const int* __restrict__ bbase,
                  int* __restrict__ offs, int* __restrict__ cursor, int n) {
  __shared__ int wsum[16];
  int tid = threadIdx.x, lane = tid & 63, wid = tid >> 6;
  int i = blockIdx.x * 1024 + tid;
  int v = (i < n) ? cnt[i] : 0;
  int s = v;
  #pragma unroll
  for (int d = 1; d < 64; d <<= 1) {
    int t = __shfl_up(s, d);
    if (lane >= d) s += t;
  }
  if (lane == 63) wsum[wid] = s;
  __syncthreads();
  if (wid == 0 && lane < 16) {
    int x = wsum[lane];
    #pragma unroll
    for (int d = 1; d < 16; d <<= 1) {
      int t = __shfl_up(x, d);
      if (lane >= d) x += t;
    }
    wsum[lane] = x;
  }
  __syncthreads();
  int woff = (wid == 0) ? 0 : wsum[wid - 1];
  if (i < n) {
    int val = bbase[blockIdx.x] + woff + s - v;
    offs[i] = val;
    cursor[i] = val;
  }
}

// scatter: cursor atomicAdd gives position; atomicExch keeps the random 4B
// write in L2 (plain store-miss was going out as 64B partial-line fabric
// writes -> 166MB WRITE_SIZE for a 9.6MB array).
__global__ __launch_bounds__(256)
void scatter_kernel(const int* __restrict__ edges, int* __restrict__ cursor,
                    int* __restrict__ csr) {
  int p = blockIdx.y;
  int e = blockIdx.x * 256 + threadIdx.x;
  if (e >= N_EDGES) return;
  const int* base = edges + (size_t)p * 2 * N_EDGES;
  int s = base[e];
  int d = base[N_EDGES + e];
  int pos = atomicAdd(&cursor[p * N_NODES + d], 1);
  atomicExch(&csr[pos], s);
}

// ---------------- GAT aggregation (no max pass, bf16 gather, x4 unroll) -------
__global__ __launch_bounds__(256)
void aggregate_kernel(const int* __restrict__ offs, const int* __restrict__ csr,
                      const unsigned int* __restrict__ featb_u,  // [N][64] 2xbf16
                      const float* __restrict__ el, const float* __restrict__ er,
                      unsigned int* __restrict__ z_u) {           // [N][64] 2xbf16
  int node = blockIdx.x * 4 + (threadIdx.x >> 6);
  if (node >= N_NODES) return;
  int lane = threadIdx.x & 63;
  int hh = lane >> 3;
  int beg = offs[node], end = offs[node + 1];
  float erh = er[node * HEADS + hh];
  float ssum = 0.f, a0 = 0.f, a1 = 0.f;
  int i = beg;
  for (; i + 3 < end; i += 4) {
    int s0 = csr[i], s1 = csr[i + 1], s2 = csr[i + 2], s3 = csr[i + 3];
    float e0 = el[s0 * HEADS + hh] + erh;
    float e1 = el[s1 * HEADS + hh] + erh;
    float e2 = el[s2 * HEADS + hh] + erh;
    float e3 = el[s3 * HEADS + hh] + erh;
    unsigned int v0 = featb_u[(size_t)s0 * 64 + lane];
    unsigned int v1 = featb_u[(size_t)s1 * 64 + lane];
    unsigned int v2 = featb_u[(size_t)s2 * 64 + lane];
    unsigned int v3 = featb_u[(size_t)s3 * 64 + lane];
    e0 = e0 > 0.f ? e0 : 0.2f * e0;
    e1 = e1 > 0.f ? e1 : 0.2f * e1;
    e2 = e2 > 0.f ? e2 : 0.2f * e2;
    e3 = e3 > 0.f ? e3 : 0.2f * e3;
    float w0 = __expf(e0), w1 = __expf(e1), w2 = __expf(e2), w3 = __expf(e3);
    ssum += (w0 + w1) + (w2 + w3);
    a0 += w0 * __uint_as_float(v0 << 16) + w1 * __uint_as_float(v1 << 16)
        + w2 * __uint_as_float(v2 << 16) + w3 * __uint_as_float(v3 << 16);
    a1 += w0 * __uint_as_float(v0 & 0xffff0000u) + w1 * __uint_as_float(v1 & 0xffff0000u)
        + w2 * __uint_as_float(v2 & 0xffff0000u) + w3 * __uint_as_float(v3 & 0xffff0000u);
  }
  for (; i < end; ++i) {
    int s0 = csr[i];
    float e0 = el[s0 * HEADS + hh] + erh;
    unsigned int v0 = featb_u[(size_t)s0 * 64 + lane];
    e0 = e0 > 0.f ? e0 : 0.2f * e0;
    float w0 = __expf(e0);
    ssum += w0;
    a0 += w0 * __uint_as_float(v0 << 16);
    a1 += w0 * __uint_as_float(v0 & 0xffff0000u);
  }
  float inv = (end > beg) ? 1.f / ssum : 0.f;
  a0 *= inv; a1 *= inv;
  a0 = a0 > 0.f ? a0 : expm1f(a0);
  a1 = a1 > 0.f ? a1 : expm1f(a1);
  unsigned int packed = (unsigned int)f2bf(a0) | ((unsigned int)f2bf(a1) << 16);
  z_u[(size_t)node * 64 + lane] = packed;
}

// ---------------- MFMA GEMM + tanh/w2 epilogue: wnode + max -------------------
__global__ __launch_bounds__(256)
void w_gemm_mfma(const unsigned short* __restrict__ Zb,    // [N,128] bf16
                 const unsigned short* __restrict__ BT,    // w1T [128][128] bf16
                 const float* __restrict__ B1, const float* __restrict__ W2,
                 float* __restrict__ wnode, unsigned int* __restrict__ wmax_enc,
                 int nrows) {
  __shared__ unsigned short As[64 * 40];
  __shared__ unsigned short Bs[128 * 40];
  __shared__ float redmax[4];
  int tid = threadIdx.x;
  int w = tid >> 6, l = tid & 63, q = l >> 4, s = l & 15;
  int row0 = blockIdx.x * 64;
  f32x4 acc[8] = {};
  for (int k0 = 0; k0 < HD; k0 += 32) {
    {
      int r = tid >> 2, c = (tid & 3) * 8;
      int gr = row0 + r;
      uint4 a0 = make_uint4(0, 0, 0, 0);
      if (gr < nrows) a0 = *(const uint4*)(Zb + (size_t)gr * HD + k0 + c);
      *(uint4*)&As[r * 40 + c] = a0;
    }
    {
      int n = tid >> 1, c = (tid & 1) * 16;
      uint4 b0 = *(const uint4*)(BT + (size_t)n * HD + k0 + c);
      uint4 b1 = *(const uint4*)(BT + (size_t)n * HD + k0 + c + 8);
      *(uint4*)&Bs[n * 40 + c]     = b0;
      *(uint4*)&Bs[n * 40 + c + 8] = b1;
    }
    __syncthreads();
    bf16x8 af = *(bf16x8*)&As[(w * 16 + s) * 40 + q * 8];
    #pragma unroll
    for (int f = 0; f < 8; ++f) {
      bf16x8 bf = *(bf16x8*)&Bs[(f * 16 + s) * 40 + q * 8];
      acc[f] = __builtin_amdgcn_mfma_f32_16x16x32_bf16(af, bf, acc[f], 0, 0, 0);
    }
    __syncthreads();
  }
  float b1v[8], w2v[8];
  #pragma unroll
  for (int f = 0; f < 8; ++f) { b1v[f] = B1[f * 16 + s]; w2v[f] = W2[f * 16 + s]; }
  float lmax = -1e30f;
  #pragma unroll
  for (int r = 0; r < 4; ++r) {
    float p = 0.f;
    #pragma unroll
    for (int f = 0; f < 8; ++f) p += tanhf(acc[f][r] + b1v[f]) * w2v[f];
    p += __shfl_xor(p, 1); p += __shfl_xor(p, 2);
    p += __shfl_xor(p, 4); p += __shfl_xor(p, 8);
    int gr = row0 + w * 16 + q * 4 + r;
    if (gr < nrows) {
      if (s == 0) wnode[gr] = p;
      lmax = fmaxf(lmax, p);
    }
  }
  #pragma unroll
  for (int d = 32; d; d >>= 1) lmax = fmaxf(lmax, __shfl_xor(lmax, d));
  if (l == 0) redmax[w] = lmax;
  __syncthreads();
  if (tid == 0) {
    float m = fmaxf(fmaxf(redmax[0], redmax[1]), fmaxf(redmax[2], redmax[3]));
    atomicMax(wmax_enc, encf(m));
  }
}

// ---------------- softmax-over-nodes fused accumulation ----------------------
__global__ __launch_bounds__(128)
void fused_acc_kernel(const unsigned short* __restrict__ zb,
                      const float* __restrict__ wnode,
                      const unsigned int* __restrict__ wmax_enc,
                      float* __restrict__ num, float* __restrict__ den, int n) {
  int t = threadIdx.x;
  float wm = decf(*wmax_enc);
  float ln = 0.f, ld = 0.f;
  for (int node = blockIdx.x; node < n; node += gridDim.x) {
    float e = __expf(wnode[node] - wm);
    ln += e * bf2f(zb[(size_t)node * HD + t]);
    ld += e;
  }
  atomicAdd(&num[t], ln);
  if (t == 0) atomicAdd(den, ld);
}

// ---------------- final ------------------------------------------------------
__global__ void final_kernel(const float* __restrict__ num, const float* __restrict__ den,
                             const float* __restrict__ PW, const float* __restrict__ PB,
                             float* __restrict__ out) {
  int t = threadIdx.x;
  if (t >= N_META * OUT_DIM) return;
  int m = t >> 3, o = t & 7;
  float inv = 1.0f / den[m];
  float s = 0.f;
  for (int k = 0; k < HD; ++k) s += num[m * HD + k] * PW[k * OUT_DIM + o];
  out[t] = s * inv + PB[o];
}

extern "C" void kernel_launch(void* const* d_in, const int* in_sizes, int n_in,
                              void* d_out, int out_size, void* d_ws, size_t ws_size,
                              hipStream_t stream) {
  (void)in_sizes; (void)n_in; (void)out_size; (void)ws_size;
  const float* h     = (const float*)d_in[0];
  const int*   edges = (const int*)d_in[1];
  const float* fcw   = (const float*)d_in[2];
  const float* al    = (const float*)d_in[3];
  const float* ar    = (const float*)d_in[4];
  const float* w1    = (const float*)d_in[5];
  const float* b1    = (const float*)d_in[6];
  const float* w2    = (const float*)d_in[7];
  const float* pw    = (const float*)d_in[8];
  const float* pb    = (const float*)d_in[9];
  float* out = (float*)d_out;

  char* ws = (char*)d_ws;
  size_t off = 0;
  auto alloc = [&](size_t bytes) -> void* {
    void* p = ws + off;
    off = (off + bytes + 255) & ~(size_t)255;
    return p;
  };
  unsigned short* featb = (unsigned short*)alloc((size_t)N_NODES * HD * 2);
  unsigned short* zb    = (unsigned short*)alloc((size_t)N_NODES * HD * 2);
  unsigned short* fcwT  = (unsigned short*)alloc((size_t)N_META * HD * IN_DIM * 2);
  unsigned short* w1T   = (unsigned short*)alloc((size_t)HD * HD * 2);
  float* el = (float*)alloc((size_t)N_NODES * HEADS * 4);
  float* er = (float*)alloc((size_t)N_NODES * HEADS * 4);
  int* cnt    = (int*)alloc((size_t)N_META * N_NODES * 4);
  int* cursor = (int*)alloc((size_t)N_META * N_NODES * 4);
  int* bsum  = (int*)alloc(256 * 4);
  int* bbase = (int*)alloc(256 * 4);
  int* offs  = (int*)alloc((size_t)(N_META * N_NODES + 1) * 4);
  int* csr   = (int*)alloc((size_t)N_META * N_EDGES * 4);
  float* wnode = (float*)alloc((size_t)N_NODES * 4);
  // numden block: num[3*128] | den[3] | wmax_enc[3]
  float* numden = (float*)alloc((N_META * HD + N_META + N_META) * 4);
  float* num = numden;
  float* den = numden + N_META * HD;
  unsigned int* wmax_enc = (unsigned int*)(numden + N_META * HD + N_META);

  hipMemsetAsync(numden, 0, (N_META * HD + N_META + N_META) * 4, stream);
  hipMemsetAsync(cnt, 0, (size_t)N_META * N_NODES * 4, stream);

  prep_kernel<<<(N_META * IN_DIM * HD + HD * HD + 255) / 256, 256, 0, stream>>>(
      fcw, w1, fcwT, w1T);

  const int NTOT = N_META * N_NODES;           // 150000
  const int NB = (NTOT + 1023) / 1024;         // 147
  dim3 egrid((N_EDGES + 255) / 256, N_META);
  hist_kernel<<<egrid, 256, 0, stream>>>(edges, cnt);
  scan1_kernel<<<NB, 1024, 0, stream>>>(cnt, bsum, NTOT);
  scan2_kernel<<<1, 64, 0, stream>>>(bsum, bbase, offs + NTOT, NB);
  scan3_kernel<<<NB, 1024, 0, stream>>>(cnt, bbase, offs, cursor, NTOT);
  scatter_kernel<<<egrid, 256, 0, stream>>>(edges, cursor, csr);

  dim3 ggrid((N_NODES + 63) / 64);
  for (int m = 0; m < N_META; ++m) {
    gemm_feat_mfma<<<ggrid, 256, 0, stream>>>(
        h, fcwT + (size_t)m * HD * IN_DIM, featb, N_NODES);
    el_er_kernel<<<(N_NODES * HEADS + 255) / 256, 256, 0, stream>>>(
        featb, al + m * HD, ar + m * HD, el, er);
    aggregate_kernel<<<(N_NODES + 3) / 4, 256, 0, stream>>>(
        offs + m * N_NODES, csr, (const unsigned int*)featb, el, er,
        (unsigned int*)zb);
    w_gemm_mfma<<<ggrid, 256, 0, stream>>>(
        zb, w1T, b1, w2, wnode, wmax_enc + m, N_NODES);
    fused_acc_kernel<<<256, 128, 0, stream>>>(
        zb, wnode, wmax_enc + m, num + m * HD, den + m, N_NODES);
  }
  final_kernel<<<1, 64, 0, stream>>>(num, den, pw, pb, out);
}

// Round 5
// 700.006 us; speedup vs baseline: 1.2087x; 1.2087x over previous
//
#include <hip/hip_runtime.h>

#define N_NODES 50000
#define N_EDGES 800000
#define N_META 3
#define IN_DIM 256
#define HD 128
#define HEADS 8
#define HID 16
#define OUT_DIM 8
#define NBKT 196          // ceil(50000/256) coarse buckets (256 nodes each)
#define TILE_E 4096       // edges per bin block

using bf16x8 = __attribute__((ext_vector_type(8))) short;
using f32x4  = __attribute__((ext_vector_type(4))) float;

__device__ __forceinline__ float bf2f(unsigned short u) {
  union { unsigned int i; float f; } x; x.i = ((unsigned int)u) << 16; return x.f;
}
__device__ __forceinline__ unsigned short f2bf(float f) {
  union { float f; unsigned int i; } x; x.f = f;
  unsigned int r = x.i + 0x7fffu + ((x.i >> 16) & 1u);
  return (unsigned short)(r >> 16);
}
__device__ __forceinline__ unsigned int encf(float f) {
  unsigned int u = __float_as_uint(f);
  return (u & 0x80000000u) ? ~u : (u | 0x80000000u);
}
__device__ __forceinline__ float decf(unsigned int u) {
  return (u & 0x80000000u) ? __uint_as_float(u & 0x7fffffffu) : __uint_as_float(~u);
}

// ---------------- prep: fcw -> fcwT bf16 [M][128][256]; w1 -> w1T bf16 [128][128]
__global__ __launch_bounds__(256)
void prep_kernel(const float* __restrict__ fcw, const float* __restrict__ w1,
                 unsigned short* __restrict__ fcwT, unsigned short* __restrict__ w1T) {
  int i = blockIdx.x * 256 + threadIdx.x;
  const int NFC = N_META * IN_DIM * HD;
  if (i < NFC) {
    int p = i / (IN_DIM * HD);
    int rem = i - p * (IN_DIM * HD);
    int k = rem / HD, n = rem - k * HD;
    fcwT[(size_t)p * HD * IN_DIM + n * IN_DIM + k] = f2bf(fcw[i]);
  } else if (i < NFC + HD * HD) {
    int j = i - NFC;
    int k = j / HD, n = j - k * HD;
    w1T[n * HD + k] = f2bf(w1[j]);
  }
}

// ------- MFMA GEMM: featb = bf16(h @ fc_w[m]); fused el/er epilogue -----------
__global__ __launch_bounds__(256)
void gemm_feat_mfma(const float* __restrict__ A,            // h [N,256] f32
                    const unsigned short* __restrict__ BT,  // fcwT [128][256] bf16
                    const float* __restrict__ AL,           // attn_l[m] [128]
                    const float* __restrict__ AR,           // attn_r[m] [128]
                    unsigned short* __restrict__ Cb,        // featb [N,128] bf16
                    float* __restrict__ el, float* __restrict__ er,
                    int nrows) {
  __shared__ unsigned short As[64 * 40];
  __shared__ unsigned short Bs[128 * 40];
  int tid = threadIdx.x;
  int w = tid >> 6, l = tid & 63, q = l >> 4, s = l & 15;
  int row0 = blockIdx.x * 64;
  f32x4 acc[8] = {};
  for (int k0 = 0; k0 < IN_DIM; k0 += 32) {
    {
      int r = tid >> 2, c = (tid & 3) * 8;
      int gr = row0 + r;
      float4 a0, a1;
      if (gr < nrows) {
        a0 = *(const float4*)(A + (size_t)gr * IN_DIM + k0 + c);
        a1 = *(const float4*)(A + (size_t)gr * IN_DIM + k0 + c + 4);
      } else {
        a0 = make_float4(0.f, 0.f, 0.f, 0.f); a1 = a0;
      }
      ushort4 u0, u1;
      u0.x = f2bf(a0.x); u0.y = f2bf(a0.y); u0.z = f2bf(a0.z); u0.w = f2bf(a0.w);
      u1.x = f2bf(a1.x); u1.y = f2bf(a1.y); u1.z = f2bf(a1.z); u1.w = f2bf(a1.w);
      *(ushort4*)&As[r * 40 + c]     = u0;
      *(ushort4*)&As[r * 40 + c + 4] = u1;
    }
    {
      int n = tid >> 1, c = (tid & 1) * 16;
      uint4 b0 = *(const uint4*)(BT + (size_t)n * IN_DIM + k0 + c);
      uint4 b1 = *(const uint4*)(BT + (size_t)n * IN_DIM + k0 + c + 8);
      *(uint4*)&Bs[n * 40 + c]     = b0;
      *(uint4*)&Bs[n * 40 + c + 8] = b1;
    }
    __syncthreads();
    bf16x8 af = *(bf16x8*)&As[(w * 16 + s) * 40 + q * 8];
    #pragma unroll
    for (int f = 0; f < 8; ++f) {
      bf16x8 bf = *(bf16x8*)&Bs[(f * 16 + s) * 40 + q * 8];
      acc[f] = __builtin_amdgcn_mfma_f32_16x16x32_bf16(af, bf, acc[f], 0, 0, 0);
    }
    __syncthreads();
  }
  // epilogue: store bf16 feat + fused el/er (head == col-frag f, dim == lane s)
  #pragma unroll
  for (int f = 0; f < 8; ++f) {
    float alv = AL[f * 16 + s], arv = AR[f * 16 + s];
    #pragma unroll
    for (int r = 0; r < 4; ++r) {
      int gr = row0 + w * 16 + q * 4 + r;
      if (gr < nrows) Cb[(size_t)gr * HD + f * 16 + s] = f2bf(acc[f][r]);
      float pl = acc[f][r] * alv, pr = acc[f][r] * arv;
      pl += __shfl_xor(pl, 1); pr += __shfl_xor(pr, 1);
      pl += __shfl_xor(pl, 2); pr += __shfl_xor(pr, 2);
      pl += __shfl_xor(pl, 4); pr += __shfl_xor(pr, 4);
      pl += __shfl_xor(pl, 8); pr += __shfl_xor(pr, 8);
      if (s == 0 && gr < nrows) {
        el[gr * HEADS + f] = pl;
        er[gr * HEADS + f] = pr;
      }
    }
  }
}

// ---------------- node-level histogram + scans -------------------------------
__global__ __launch_bounds__(256)
void hist_kernel(const int* __restrict__ edges, int* __restrict__ cnt) {
  int p = blockIdx.y;
  int e = blockIdx.x * 256 + threadIdx.x;
  if (e < N_EDGES)
    atomicAdd(&cnt[p * N_NODES + edges[(size_t)p * 2 * N_EDGES + N_EDGES + e]], 1);
}

__global__ __launch_bounds__(1024)
void scan1_kernel(const int* __restrict__ cnt, int* __restrict__ bsum, int n) {
  __shared__ int ws[16];
  int tid = threadIdx.x, lane = tid & 63, wid = tid >> 6;
  int i = blockIdx.x * 1024 + tid;
  int v = (i < n) ? cnt[i] : 0;
  #pragma unroll
  for (int d = 32; d; d >>= 1) v += __shfl_xor(v, d);
  if (lane == 0) ws[wid] = v;
  __syncthreads();
  if (tid == 0) {
    int s = 0;
    #pragma unroll
    for (int k = 0; k < 16; ++k) s += ws[k];
    bsum[blockIdx.x] = s;
  }
}

__global__ __launch_bounds__(64)
void scan2_kernel(const int* __restrict__ bsum, int* __restrict__ bbase,
                  int* __restrict__ offs_end, int nb) {
  int lane = threadIdx.x;
  int carry = 0;
  for (int base = 0; base < nb; base += 64) {
    int i = base + lane;
    int v = (i < nb) ? bsum[i] : 0;
    int s = v;
    #pragma unroll
    for (int d = 1; d < 64; d <<= 1) {
      int t = __shfl_up(s, d);
      if (lane >= d) s += t;
    }
    if (i < nb) bbase[i] = carry + s - v;
    carry += __shfl(s, 63);
  }
  if (lane == 0) *offs_end = carry;
}

__global__ __launch_bounds__(1024)
void scan3_kernel(const int* __restrict__ cnt, const int* __restrict__ bbase,
                  int* __restrict__ offs, int n) {
  __shared__ int wsum[16];
  int tid = threadIdx.x, lane = tid & 63, wid = tid >> 6;
  int i = blockIdx.x * 1024 + tid;
  int v = (i < n) ? cnt[i] : 0;
  int s = v;
  #pragma unroll
  for (int d = 1; d < 64; d <<= 1) {
    int t = __shfl_up(s, d);
    if (lane >= d) s += t;
  }
  if (lane == 63) wsum[wid] = s;
  __syncthreads();
  if (wid == 0 && lane < 16) {
    int x = wsum[lane];
    #pragma unroll
    for (int d = 1; d < 16; d <<= 1) {
      int t = __shfl_up(x, d);
      if (lane >= d) x += t;
    }
    wsum[lane] = x;
  }
  __syncthreads();
  int woff = (wid == 0) ? 0 : wsum[wid - 1];
  if (i < n) offs[i] = bbase[blockIdx.x] + woff + s - v;
}

// ---------------- two-level counting sort ------------------------------------
__global__ __launch_bounds__(256)
void gcur_init_kernel(const int* __restrict__ offs, int* __restrict__ gcur) {
  int bb = blockIdx.x * 256 + threadIdx.x;
  if (bb < N_META * NBKT) {
    int p = bb / NBKT, b = bb - p * NBKT;
    gcur[bb] = offs[p * N_NODES + b * 256];
  }
}

// Pass A: bin edges into coarse buckets with append-run (coalesced) writes.
// record = (dst&255)<<16 | src  (src < 50000 < 2^16)
__global__ __launch_bounds__(256)
void bin_kernel(const int* __restrict__ edges, int* __restrict__ gcur,
                unsigned int* __restrict__ bktbuf) {
  __shared__ int hist[NBKT];
  __shared__ int gbase[NBKT];
  __shared__ int fill[NBKT];
  int p = blockIdx.y;
  int e0 = blockIdx.x * TILE_E;
  int t = threadIdx.x;
  const int* src = edges + (size_t)p * 2 * N_EDGES;
  const int* dst = src + N_EDGES;
  for (int i = t; i < NBKT; i += 256) { hist[i] = 0; fill[i] = 0; }
  __syncthreads();
  for (int i = t; i < TILE_E; i += 256) {
    int e = e0 + i;
    if (e < N_EDGES) atomicAdd(&hist[dst[e] >> 8], 1);
  }
  __syncthreads();
  for (int i = t; i < NBKT; i += 256)
    gbase[i] = atomicAdd(&gcur[p * NBKT + i], hist[i]);
  __syncthreads();
  for (int i = t; i < TILE_E; i += 256) {
    int e = e0 + i;
    if (e < N_EDGES) {
      int d = dst[e];
      int b = d >> 8;
      int r = atomicAdd(&fill[b], 1);
      bktbuf[gbase[b] + r] = ((unsigned int)(d & 255) << 16) | (unsigned int)src[e];
    }
  }
}

// Pass B: within each bucket (one block = one XCD L2 window), exact CSR scatter.
__global__ __launch_bounds__(256)
void csr_scatter_kernel(const int* __restrict__ offs,
                        const unsigned int* __restrict__ bktbuf,
                        int* __restrict__ csr) {
  __shared__ int cur[256];
  int p = blockIdx.y, b = blockIdx.x, t = threadIdx.x;
  int node0 = b * 256;
  int nn = min(256, N_NODES - node0);
  int gi0 = p * N_NODES + node0;
  if (t < nn) cur[t] = offs[gi0 + t];
  __syncthreads();
  int S = offs[gi0];
  int E = offs[gi0 + nn];
  for (int i = S + t; i < E; i += 256) {
    unsigned int rec = bktbuf[i];
    int dl = rec >> 16;
    int s = rec & 0xffff;
    int pos = atomicAdd(&cur[dl], 1);
    csr[pos] = s;
  }
}

// ---------------- GAT aggregation (no max pass, bf16 gather, x4 unroll) -------
__global__ __launch_bounds__(256)
void aggregate_kernel(const int* __restrict__ offs, const int* __restrict__ csr,
                      const unsigned int* __restrict__ featb_u,  // [N][64] 2xbf16
                      const float* __restrict__ el, const float* __restrict__ er,
                      unsigned int* __restrict__ z_u) {           // [N][64] 2xbf16
  int node = blockIdx.x * 4 + (threadIdx.x >> 6);
  if (node >= N_NODES) return;
  int lane = threadIdx.x & 63;
  int hh = lane >> 3;
  int beg = offs[node], end = offs[node + 1];
  float erh = er[node * HEADS + hh];
  float ssum = 0.f, a0 = 0.f, a1 = 0.f;
  int i = beg;
  for (; i + 3 < end; i += 4) {
    int s0 = csr[i], s1 = csr[i + 1], s2 = csr[i + 2], s3 = csr[i + 3];
    float e0 = el[s0 * HEADS + hh] + erh;
    float e1 = el[s1 * HEADS + hh] + erh;
    float e2 = el[s2 * HEADS + hh] + erh;
    float e3 = el[s3 * HEADS + hh] + erh;
    unsigned int v0 = featb_u[(size_t)s0 * 64 + lane];
    unsigned int v1 = featb_u[(size_t)s1 * 64 + lane];
    unsigned int v2 = featb_u[(size_t)s2 * 64 + lane];
    unsigned int v3 = featb_u[(size_t)s3 * 64 + lane];
    e0 = e0 > 0.f ? e0 : 0.2f * e0;
    e1 = e1 > 0.f ? e1 : 0.2f * e1;
    e2 = e2 > 0.f ? e2 : 0.2f * e2;
    e3 = e3 > 0.f ? e3 : 0.2f * e3;
    float w0 = __expf(e0), w1 = __expf(e1), w2 = __expf(e2), w3 = __expf(e3);
    ssum += (w0 + w1) + (w2 + w3);
    a0 += w0 * __uint_as_float(v0 << 16) + w1 * __uint_as_float(v1 << 16)
        + w2 * __uint_as_float(v2 << 16) + w3 * __uint_as_float(v3 << 16);
    a1 += w0 * __uint_as_float(v0 & 0xffff0000u) + w1 * __uint_as_float(v1 & 0xffff0000u)
        + w2 * __uint_as_float(v2 & 0xffff0000u) + w3 * __uint_as_float(v3 & 0xffff0000u);
  }
  for (; i < end; ++i) {
    int s0 = csr[i];
    float e0 = el[s0 * HEADS + hh] + erh;
    unsigned int v0 = featb_u[(size_t)s0 * 64 + lane];
    e0 = e0 > 0.f ? e0 : 0.2f * e0;
    float w0 = __expf(e0);
    ssum += w0;
    a0 += w0 * __uint_as_float(v0 << 16);
    a1 += w0 * __uint_as_float(v0 & 0xffff0000u);
  }
  float inv = (end > beg) ? 1.f / ssum : 0.f;
  a0 *= inv; a1 *= inv;
  a0 = a0 > 0.f ? a0 : expm1f(a0);
  a1 = a1 > 0.f ? a1 : expm1f(a1);
  unsigned int packed = (unsigned int)f2bf(a0) | ((unsigned int)f2bf(a1) << 16);
  z_u[(size_t)node * 64 + lane] = packed;
}

// ---------------- MFMA GEMM + tanh/w2 epilogue: wnode + max -------------------
__global__ __launch_bounds__(256)
void w_gemm_mfma(const unsigned short* __restrict__ Zb,    // [N,128] bf16
                 const unsigned short* __restrict__ BT,    // w1T [128][128] bf16
                 const float* __restrict__ B1, const float* __restrict__ W2,
                 float* __restrict__ wnode, unsigned int* __restrict__ wmax_enc,
                 int nrows) {
  __shared__ unsigned short As[64 * 40];
  __shared__ unsigned short Bs[128 * 40];
  __shared__ float redmax[4];
  int tid = threadIdx.x;
  int w = tid >> 6, l = tid & 63, q = l >> 4, s = l & 15;
  int row0 = blockIdx.x * 64;
  f32x4 acc[8] = {};
  for (int k0 = 0; k0 < HD; k0 += 32) {
    {
      int r = tid >> 2, c = (tid & 3) * 8;
      int gr = row0 + r;
      uint4 a0 = make_uint4(0, 0, 0, 0);
      if (gr < nrows) a0 = *(const uint4*)(Zb + (size_t)gr * HD + k0 + c);
      *(uint4*)&As[r * 40 + c] = a0;
    }
    {
      int n = tid >> 1, c = (tid & 1) * 16;
      uint4 b0 = *(const uint4*)(BT + (size_t)n * HD + k0 + c);
      uint4 b1 = *(const uint4*)(BT + (size_t)n * HD + k0 + c + 8);
      *(uint4*)&Bs[n * 40 + c]     = b0;
      *(uint4*)&Bs[n * 40 + c + 8] = b1;
    }
    __syncthreads();
    bf16x8 af = *(bf16x8*)&As[(w * 16 + s) * 40 + q * 8];
    #pragma unroll
    for (int f = 0; f < 8; ++f) {
      bf16x8 bf = *(bf16x8*)&Bs[(f * 16 + s) * 40 + q * 8];
      acc[f] = __builtin_amdgcn_mfma_f32_16x16x32_bf16(af, bf, acc[f], 0, 0, 0);
    }
    __syncthreads();
  }
  float b1v[8], w2v[8];
  #pragma unroll
  for (int f = 0; f < 8; ++f) { b1v[f] = B1[f * 16 + s]; w2v[f] = W2[f * 16 + s]; }
  float lmax = -1e30f;
  #pragma unroll
  for (int r = 0; r < 4; ++r) {
    float p = 0.f;
    #pragma unroll
    for (int f = 0; f < 8; ++f) p += tanhf(acc[f][r] + b1v[f]) * w2v[f];
    p += __shfl_xor(p, 1); p += __shfl_xor(p, 2);
    p += __shfl_xor(p, 4); p += __shfl_xor(p, 8);
    int gr = row0 + w * 16 + q * 4 + r;
    if (gr < nrows) {
      if (s == 0) wnode[gr] = p;
      lmax = fmaxf(lmax, p);
    }
  }
  #pragma unroll
  for (int d = 32; d; d >>= 1) lmax = fmaxf(lmax, __shfl_xor(lmax, d));
  if (l == 0) redmax[w] = lmax;
  __syncthreads();
  if (tid == 0) {
    float m = fmaxf(fmaxf(redmax[0], redmax[1]), fmaxf(redmax[2], redmax[3]));
    atomicMax(wmax_enc, encf(m));
  }
}

// ---------------- softmax-over-nodes fused accumulation ----------------------
__global__ __launch_bounds__(128)
void fused_acc_kernel(const unsigned short* __restrict__ zb,
                      const float* __restrict__ wnode,
                      const unsigned int* __restrict__ wmax_enc,
                      float* __restrict__ num, float* __restrict__ den, int n) {
  int t = threadIdx.x;
  float wm = decf(*wmax_enc);
  float ln = 0.f, ld = 0.f;
  for (int node = blockIdx.x; node < n; node += gridDim.x) {
    float e = __expf(wnode[node] - wm);
    ln += e * bf2f(zb[(size_t)node * HD + t]);
    ld += e;
  }
  atomicAdd(&num[t], ln);
  if (t == 0) atomicAdd(den, ld);
}

// ---------------- final ------------------------------------------------------
__global__ void final_kernel(const float* __restrict__ num, const float* __restrict__ den,
                             const float* __restrict__ PW, const float* __restrict__ PB,
                             float* __restrict__ out) {
  int t = threadIdx.x;
  if (t >= N_META * OUT_DIM) return;
  int m = t >> 3, o = t & 7;
  float inv = 1.0f / den[m];
  float s = 0.f;
  for (int k = 0; k < HD; ++k) s += num[m * HD + k] * PW[k * OUT_DIM + o];
  out[t] = s * inv + PB[o];
}

extern "C" void kernel_launch(void* const* d_in, const int* in_sizes, int n_in,
                              void* d_out, int out_size, void* d_ws, size_t ws_size,
                              hipStream_t stream) {
  (void)in_sizes; (void)n_in; (void)out_size; (void)ws_size;
  const float* h     = (const float*)d_in[0];
  const int*   edges = (const int*)d_in[1];
  const float* fcw   = (const float*)d_in[2];
  const float* al    = (const float*)d_in[3];
  const float* ar    = (const float*)d_in[4];
  const float* w1    = (const float*)d_in[5];
  const float* b1    = (const float*)d_in[6];
  const float* w2    = (const float*)d_in[7];
  const float* pw    = (const float*)d_in[8];
  const float* pb    = (const float*)d_in[9];
  float* out = (float*)d_out;

  char* ws = (char*)d_ws;
  size_t off = 0;
  auto alloc = [&](size_t bytes) -> void* {
    void* p = ws + off;
    off = (off + bytes + 255) & ~(size_t)255;
    return p;
  };
  unsigned short* featb = (unsigned short*)alloc((size_t)N_NODES * HD * 2);
  unsigned short* zb    = (unsigned short*)alloc((size_t)N_NODES * HD * 2);
  unsigned short* fcwT  = (unsigned short*)alloc((size_t)N_META * HD * IN_DIM * 2);
  unsigned short* w1T   = (unsigned short*)alloc((size_t)HD * HD * 2);
  float* el = (float*)alloc((size_t)N_NODES * HEADS * 4);
  float* er = (float*)alloc((size_t)N_NODES * HEADS * 4);
  int* cnt   = (int*)alloc((size_t)N_META * N_NODES * 4);
  int* gcur  = (int*)alloc((size_t)N_META * NBKT * 4);
  int* bsum  = (int*)alloc(256 * 4);
  int* bbase = (int*)alloc(256 * 4);
  int* offs  = (int*)alloc((size_t)(N_META * N_NODES + 1) * 4);
  unsigned int* bktbuf = (unsigned int*)alloc((size_t)N_META * N_EDGES * 4);
  int* csr   = (int*)alloc((size_t)N_META * N_EDGES * 4);
  float* wnode = (float*)alloc((size_t)N_NODES * 4);
  // numden block: num[3*128] | den[3] | wmax_enc[3]
  float* numden = (float*)alloc((N_META * HD + N_META + N_META) * 4);
  float* num = numden;
  float* den = numden + N_META * HD;
  unsigned int* wmax_enc = (unsigned int*)(numden + N_META * HD + N_META);

  hipMemsetAsync(numden, 0, (N_META * HD + N_META + N_META) * 4, stream);
  hipMemsetAsync(cnt, 0, (size_t)N_META * N_NODES * 4, stream);

  prep_kernel<<<(N_META * IN_DIM * HD + HD * HD + 255) / 256, 256, 0, stream>>>(
      fcw, w1, fcwT, w1T);

  const int NTOT = N_META * N_NODES;           // 150000
  const int NB = (NTOT + 1023) / 1024;         // 147
  dim3 egrid((N_EDGES + 255) / 256, N_META);
  hist_kernel<<<egrid, 256, 0, stream>>>(edges, cnt);
  scan1_kernel<<<NB, 1024, 0, stream>>>(cnt, bsum, NTOT);
  scan2_kernel<<<1, 64, 0, stream>>>(bsum, bbase, offs + NTOT, NB);
  scan3_kernel<<<NB, 1024, 0, stream>>>(cnt, bbase, offs, NTOT);
  gcur_init_kernel<<<(N_META * NBKT + 255) / 256, 256, 0, stream>>>(offs, gcur);
  dim3 bgrid((N_EDGES + TILE_E - 1) / TILE_E, N_META);
  bin_kernel<<<bgrid, 256, 0, stream>>>(edges, gcur, bktbuf);
  dim3 sgrid(NBKT, N_META);
  csr_scatter_kernel<<<sgrid, 256, 0, stream>>>(offs, bktbuf, csr);

  dim3 ggrid((N_NODES + 63) / 64);
  for (int m = 0; m < N_META; ++m) {
    gemm_feat_mfma<<<ggrid, 256, 0, stream>>>(
        h, fcwT + (size_t)m * HD * IN_DIM, al + m * HD, ar + m * HD,
        featb, el, er, N_NODES);
    aggregate_kernel<<<(N_NODES + 3) / 4, 256, 0, stream>>>(
        offs + m * N_NODES, csr, (const unsigned int*)featb, el, er,
        (unsigned int*)zb);
    w_gemm_mfma<<<ggrid, 256, 0, stream>>>(
        zb, w1T, b1, w2, wnode, wmax_enc + m, N_NODES);
    fused_acc_kernel<<<256, 128, 0, stream>>>(
        zb, wnode, wmax_enc + m, num + m * HD, den + m, N_NODES);
  }
  final_kernel<<<1, 64, 0, stream>>>(num, den, pw, pb, out);
}

// Round 6
// 580.127 us; speedup vs baseline: 1.4585x; 1.2066x over previous
//
#include <hip/hip_runtime.h>

#define N_NODES 50000
#define N_EDGES 800000
#define N_META 3
#define IN_DIM 256
#define HD 128
#define HEADS 8
#define HID 16
#define OUT_DIM 8
#define NBKT 196          // ceil(50000/256) coarse buckets (256 nodes each)
#define TILE_E 4096       // edges per bin/bhist block

using bf16x8 = __attribute__((ext_vector_type(8))) short;
using f32x4  = __attribute__((ext_vector_type(4))) float;

__device__ __forceinline__ float bf2f(unsigned short u) {
  union { unsigned int i; float f; } x; x.i = ((unsigned int)u) << 16; return x.f;
}
__device__ __forceinline__ unsigned short f2bf(float f) {
  union { float f; unsigned int i; } x; x.f = f;
  unsigned int r = x.i + 0x7fffu + ((x.i >> 16) & 1u);
  return (unsigned short)(r >> 16);
}

// ---------------- prep: fcw -> fcwT bf16 [M][128][256]; w1 -> w1T bf16 [128][128]
__global__ __launch_bounds__(256)
void prep_kernel(const float* __restrict__ fcw, const float* __restrict__ w1,
                 unsigned short* __restrict__ fcwT, unsigned short* __restrict__ w1T) {
  int i = blockIdx.x * 256 + threadIdx.x;
  const int NFC = N_META * IN_DIM * HD;
  if (i < NFC) {
    int p = i / (IN_DIM * HD);
    int rem = i - p * (IN_DIM * HD);
    int k = rem / HD, n = rem - k * HD;
    fcwT[(size_t)p * HD * IN_DIM + n * IN_DIM + k] = f2bf(fcw[i]);
  } else if (i < NFC + HD * HD) {
    int j = i - NFC;
    int k = j / HD, n = j - k * HD;
    w1T[n * HD + k] = f2bf(w1[j]);
  }
}

// ------- MFMA GEMM: featb = bf16(h @ fc_w[m]); fused el/er epilogue -----------
__global__ __launch_bounds__(256)
void gemm_feat_mfma(const float* __restrict__ A,            // h [N,256] f32
                    const unsigned short* __restrict__ BT,  // fcwT [128][256] bf16
                    const float* __restrict__ AL,           // attn_l[m] [128]
                    const float* __restrict__ AR,           // attn_r[m] [128]
                    unsigned short* __restrict__ Cb,        // featb [N,128] bf16
                    float* __restrict__ el, float* __restrict__ er,
                    int nrows) {
  __shared__ unsigned short As[64 * 40];
  __shared__ unsigned short Bs[128 * 40];
  int tid = threadIdx.x;
  int w = tid >> 6, l = tid & 63, q = l >> 4, s = l & 15;
  int row0 = blockIdx.x * 64;
  f32x4 acc[8] = {};
  for (int k0 = 0; k0 < IN_DIM; k0 += 32) {
    {
      int r = tid >> 2, c = (tid & 3) * 8;
      int gr = row0 + r;
      float4 a0, a1;
      if (gr < nrows) {
        a0 = *(const float4*)(A + (size_t)gr * IN_DIM + k0 + c);
        a1 = *(const float4*)(A + (size_t)gr * IN_DIM + k0 + c + 4);
      } else {
        a0 = make_float4(0.f, 0.f, 0.f, 0.f); a1 = a0;
      }
      ushort4 u0, u1;
      u0.x = f2bf(a0.x); u0.y = f2bf(a0.y); u0.z = f2bf(a0.z); u0.w = f2bf(a0.w);
      u1.x = f2bf(a1.x); u1.y = f2bf(a1.y); u1.z = f2bf(a1.z); u1.w = f2bf(a1.w);
      *(ushort4*)&As[r * 40 + c]     = u0;
      *(ushort4*)&As[r * 40 + c + 4] = u1;
    }
    {
      int n = tid >> 1, c = (tid & 1) * 16;
      uint4 b0 = *(const uint4*)(BT + (size_t)n * IN_DIM + k0 + c);
      uint4 b1 = *(const uint4*)(BT + (size_t)n * IN_DIM + k0 + c + 8);
      *(uint4*)&Bs[n * 40 + c]     = b0;
      *(uint4*)&Bs[n * 40 + c + 8] = b1;
    }
    __syncthreads();
    bf16x8 af = *(bf16x8*)&As[(w * 16 + s) * 40 + q * 8];
    #pragma unroll
    for (int f = 0; f < 8; ++f) {
      bf16x8 bf = *(bf16x8*)&Bs[(f * 16 + s) * 40 + q * 8];
      acc[f] = __builtin_amdgcn_mfma_f32_16x16x32_bf16(af, bf, acc[f], 0, 0, 0);
    }
    __syncthreads();
  }
  // epilogue: store bf16 feat + fused el/er (head == col-frag f, dim == lane s)
  #pragma unroll
  for (int f = 0; f < 8; ++f) {
    float alv = AL[f * 16 + s], arv = AR[f * 16 + s];
    #pragma unroll
    for (int r = 0; r < 4; ++r) {
      int gr = row0 + w * 16 + q * 4 + r;
      if (gr < nrows) Cb[(size_t)gr * HD + f * 16 + s] = f2bf(acc[f][r]);
      float pl = acc[f][r] * alv, pr = acc[f][r] * arv;
      pl += __shfl_xor(pl, 1); pr += __shfl_xor(pr, 1);
      pl += __shfl_xor(pl, 2); pr += __shfl_xor(pr, 2);
      pl += __shfl_xor(pl, 4); pr += __shfl_xor(pr, 4);
      pl += __shfl_xor(pl, 8); pr += __shfl_xor(pr, 8);
      if (s == 0 && gr < nrows) {
        el[gr * HEADS + f] = pl;
        er[gr * HEADS + f] = pr;
      }
    }
  }
}

// ---------------- coarse-bucket histogram (LDS, then 196 atomics/block) -------
__global__ __launch_bounds__(256)
void bhist_kernel(const int* __restrict__ edges, int* __restrict__ bcnt) {
  __shared__ int lh[NBKT];
  int p = blockIdx.y;
  int e0 = blockIdx.x * TILE_E;
  int t = threadIdx.x;
  const int* dst = edges + (size_t)p * 2 * N_EDGES + N_EDGES;
  for (int i = t; i < NBKT; i += 256) lh[i] = 0;
  __syncthreads();
  for (int i = t; i < TILE_E; i += 256) {
    int e = e0 + i;
    if (e < N_EDGES) atomicAdd(&lh[dst[e] >> 8], 1);
  }
  __syncthreads();
  for (int i = t; i < NBKT; i += 256)
    if (lh[i]) atomicAdd(&bcnt[p * NBKT + i], lh[i]);
}

// ---------------- scan 588 bucket counts -> bucket bases + bin cursors -------
__global__ __launch_bounds__(1024)
void bscan_kernel(const int* __restrict__ bcnt, int* __restrict__ bbase,
                  int* __restrict__ gcur) {
  __shared__ int wsum[16];
  const int n = N_META * NBKT;
  int tid = threadIdx.x, lane = tid & 63, wid = tid >> 6;
  int v = (tid < n) ? bcnt[tid] : 0;
  int s = v;
  #pragma unroll
  for (int d = 1; d < 64; d <<= 1) {
    int t = __shfl_up(s, d);
    if (lane >= d) s += t;
  }
  if (lane == 63) wsum[wid] = s;
  __syncthreads();
  if (wid == 0 && lane < 16) {
    int x = wsum[lane];
    #pragma unroll
    for (int d = 1; d < 16; d <<= 1) {
      int t = __shfl_up(x, d);
      if (lane >= d) x += t;
    }
    wsum[lane] = x;
  }
  __syncthreads();
  int woff = (wid == 0) ? 0 : wsum[wid - 1];
  if (tid < n) {
    int excl = woff + s - v;
    bbase[tid] = excl;
    gcur[tid] = excl;
  }
  if (tid == 0) bbase[n] = wsum[15];
}

// ---------------- Pass A: bin edges into coarse buckets (append runs) ---------
// record = (dst&255)<<16 | src  (src < 50000 < 2^16)
__global__ __launch_bounds__(256)
void bin_kernel(const int* __restrict__ edges, int* __restrict__ gcur,
                unsigned int* __restrict__ bktbuf) {
  __shared__ int hist[NBKT];
  __shared__ int gbase[NBKT];
  __shared__ int fill[NBKT];
  int p = blockIdx.y;
  int e0 = blockIdx.x * TILE_E;
  int t = threadIdx.x;
  const int* src = edges + (size_t)p * 2 * N_EDGES;
  const int* dst = src + N_EDGES;
  for (int i = t; i < NBKT; i += 256) { hist[i] = 0; fill[i] = 0; }
  __syncthreads();
  for (int i = t; i < TILE_E; i += 256) {
    int e = e0 + i;
    if (e < N_EDGES) atomicAdd(&hist[dst[e] >> 8], 1);
  }
  __syncthreads();
  for (int i = t; i < NBKT; i += 256)
    gbase[i] = hist[i] ? atomicAdd(&gcur[p * NBKT + i], hist[i]) : 0;
  __syncthreads();
  for (int i = t; i < TILE_E; i += 256) {
    int e = e0 + i;
    if (e < N_EDGES) {
      int d = dst[e];
      int b = d >> 8;
      int r = atomicAdd(&fill[b], 1);
      bktbuf[gbase[b] + r] = ((unsigned int)(d & 255) << 16) | (unsigned int)src[e];
    }
  }
}

// ---- Pass B: per bucket: LDS hist+scan -> offs (coalesced) + exact scatter ---
__global__ __launch_bounds__(256)
void csr_sort_kernel(const int* __restrict__ bbase,
                     const unsigned int* __restrict__ bktbuf,
                     int* __restrict__ offs, int* __restrict__ csr) {
  __shared__ int lh[256];
  __shared__ int cur[256];
  __shared__ int wsum[4];
  int p = blockIdx.y, b = blockIdx.x, t = threadIdx.x;
  int lane = t & 63, wid = t >> 6;
  int idx = p * NBKT + b;
  int S = bbase[idx], E = bbase[idx + 1];
  int node0 = b * 256;
  int nn = min(256, N_NODES - node0);
  lh[t] = 0;
  __syncthreads();
  for (int i = S + t; i < E; i += 256) atomicAdd(&lh[bktbuf[i] >> 16], 1);
  __syncthreads();
  int v = lh[t];
  int s = v;
  #pragma unroll
  for (int d = 1; d < 64; d <<= 1) {
    int x = __shfl_up(s, d);
    if (lane >= d) s += x;
  }
  if (lane == 63) wsum[wid] = s;
  __syncthreads();
  int woff = 0;
  #pragma unroll
  for (int k = 0; k < 4; ++k) if (k < wid) woff += wsum[k];
  int excl = S + woff + s - v;
  if (t < nn) offs[p * N_NODES + node0 + t] = excl;
  cur[t] = excl;
  if (p == N_META - 1 && b == NBKT - 1 && t == 0)
    offs[N_META * N_NODES] = E;
  __syncthreads();
  for (int i = S + t; i < E; i += 256) {
    unsigned int rec = bktbuf[i];
    int pos = atomicAdd(&cur[rec >> 16], 1);
    csr[pos] = (int)(rec & 0xffffu);
  }
}

// ---------------- GAT aggregation (no max pass, bf16 gather, x4 unroll) -------
__global__ __launch_bounds__(256)
void aggregate_kernel(const int* __restrict__ offs, const int* __restrict__ csr,
                      const unsigned int* __restrict__ featb_u,  // [N][64] 2xbf16
                      const float* __restrict__ el, const float* __restrict__ er,
                      unsigned int* __restrict__ z_u) {           // [N][64] 2xbf16
  int node = blockIdx.x * 4 + (threadIdx.x >> 6);
  if (node >= N_NODES) return;
  int lane = threadIdx.x & 63;
  int hh = lane >> 3;
  int beg = offs[node], end = offs[node + 1];
  float erh = er[node * HEADS + hh];
  float ssum = 0.f, a0 = 0.f, a1 = 0.f;
  int i = beg;
  for (; i + 3 < end; i += 4) {
    int s0 = csr[i], s1 = csr[i + 1], s2 = csr[i + 2], s3 = csr[i + 3];
    float e0 = el[s0 * HEADS + hh] + erh;
    float e1 = el[s1 * HEADS + hh] + erh;
    float e2 = el[s2 * HEADS + hh] + erh;
    float e3 = el[s3 * HEADS + hh] + erh;
    unsigned int v0 = featb_u[(size_t)s0 * 64 + lane];
    unsigned int v1 = featb_u[(size_t)s1 * 64 + lane];
    unsigned int v2 = featb_u[(size_t)s2 * 64 + lane];
    unsigned int v3 = featb_u[(size_t)s3 * 64 + lane];
    e0 = e0 > 0.f ? e0 : 0.2f * e0;
    e1 = e1 > 0.f ? e1 : 0.2f * e1;
    e2 = e2 > 0.f ? e2 : 0.2f * e2;
    e3 = e3 > 0.f ? e3 : 0.2f * e3;
    float w0 = __expf(e0), w1 = __expf(e1), w2 = __expf(e2), w3 = __expf(e3);
    ssum += (w0 + w1) + (w2 + w3);
    a0 += w0 * __uint_as_float(v0 << 16) + w1 * __uint_as_float(v1 << 16)
        + w2 * __uint_as_float(v2 << 16) + w3 * __uint_as_float(v3 << 16);
    a1 += w0 * __uint_as_float(v0 & 0xffff0000u) + w1 * __uint_as_float(v1 & 0xffff0000u)
        + w2 * __uint_as_float(v2 & 0xffff0000u) + w3 * __uint_as_float(v3 & 0xffff0000u);
  }
  for (; i < end; ++i) {
    int s0 = csr[i];
    float e0 = el[s0 * HEADS + hh] + erh;
    unsigned int v0 = featb_u[(size_t)s0 * 64 + lane];
    e0 = e0 > 0.f ? e0 : 0.2f * e0;
    float w0 = __expf(e0);
    ssum += w0;
    a0 += w0 * __uint_as_float(v0 << 16);
    a1 += w0 * __uint_as_float(v0 & 0xffff0000u);
  }
  float inv = (end > beg) ? 1.f / ssum : 0.f;
  a0 *= inv; a1 *= inv;
  a0 = a0 > 0.f ? a0 : expm1f(a0);
  a1 = a1 > 0.f ? a1 : expm1f(a1);
  unsigned int packed = (unsigned int)f2bf(a0) | ((unsigned int)f2bf(a1) << 16);
  z_u[(size_t)node * 64 + lane] = packed;
}

// ---------------- MFMA GEMM + tanh/w2 epilogue: wnode -------------------------
__global__ __launch_bounds__(256)
void w_gemm_mfma(const unsigned short* __restrict__ Zb,    // [N,128] bf16
                 const unsigned short* __restrict__ BT,    // w1T [128][128] bf16
                 const float* __restrict__ B1, const float* __restrict__ W2,
                 float* __restrict__ wnode, int nrows) {
  __shared__ unsigned short As[64 * 40];
  __shared__ unsigned short Bs[128 * 40];
  int tid = threadIdx.x;
  int w = tid >> 6, l = tid & 63, q = l >> 4, s = l & 15;
  int row0 = blockIdx.x * 64;
  f32x4 acc[8] = {};
  for (int k0 = 0; k0 < HD; k0 += 32) {
    {
      int r = tid >> 2, c = (tid & 3) * 8;
      int gr = row0 + r;
      uint4 a0 = make_uint4(0, 0, 0, 0);
      if (gr < nrows) a0 = *(const uint4*)(Zb + (size_t)gr * HD + k0 + c);
      *(uint4*)&As[r * 40 + c] = a0;
    }
    {
      int n = tid >> 1, c = (tid & 1) * 16;
      uint4 b0 = *(const uint4*)(BT + (size_t)n * HD + k0 + c);
      uint4 b1 = *(const uint4*)(BT + (size_t)n * HD + k0 + c + 8);
      *(uint4*)&Bs[n * 40 + c]     = b0;
      *(uint4*)&Bs[n * 40 + c + 8] = b1;
    }
    __syncthreads();
    bf16x8 af = *(bf16x8*)&As[(w * 16 + s) * 40 + q * 8];
    #pragma unroll
    for (int f = 0; f < 8; ++f) {
      bf16x8 bf = *(bf16x8*)&Bs[(f * 16 + s) * 40 + q * 8];
      acc[f] = __builtin_amdgcn_mfma_f32_16x16x32_bf16(af, bf, acc[f], 0, 0, 0);
    }
    __syncthreads();
  }
  float b1v[8], w2v[8];
  #pragma unroll
  for (int f = 0; f < 8; ++f) { b1v[f] = B1[f * 16 + s]; w2v[f] = W2[f * 16 + s]; }
  #pragma unroll
  for (int r = 0; r < 4; ++r) {
    float p = 0.f;
    #pragma unroll
    for (int f = 0; f < 8; ++f) p += tanhf(acc[f][r] + b1v[f]) * w2v[f];
    p += __shfl_xor(p, 1); p += __shfl_xor(p, 2);
    p += __shfl_xor(p, 4); p += __shfl_xor(p, 8);
    int gr = row0 + w * 16 + q * 4 + r;
    if (s == 0 && gr < nrows) wnode[gr] = p;
  }
}

// ---------------- softmax-over-nodes fused accumulation (unshifted exp) -------
// |w| <= ~1 (0.05-scale weights, tanh in (-1,1)): exp never overflows; softmax
// is shift-invariant so skipping the global max pass is exact.
__global__ __launch_bounds__(128)
void fused_acc_kernel(const unsigned short* __restrict__ zb,
                      const float* __restrict__ wnode,
                      float* __restrict__ num, float* __restrict__ den, int n) {
  int t = threadIdx.x;
  float ln = 0.f, ld = 0.f;
  for (int node = blockIdx.x; node < n; node += gridDim.x) {
    float e = __expf(wnode[node]);
    ln += e * bf2f(zb[(size_t)node * HD + t]);
    ld += e;
  }
  atomicAdd(&num[t], ln);
  if (t == 0) atomicAdd(den, ld);
}

// ---------------- final ------------------------------------------------------
__global__ void final_kernel(const float* __restrict__ num, const float* __restrict__ den,
                             const float* __restrict__ PW, const float* __restrict__ PB,
                             float* __restrict__ out) {
  int t = threadIdx.x;
  if (t >= N_META * OUT_DIM) return;
  int m = t >> 3, o = t & 7;
  float inv = 1.0f / den[m];
  float s = 0.f;
  for (int k = 0; k < HD; ++k) s += num[m * HD + k] * PW[k * OUT_DIM + o];
  out[t] = s * inv + PB[o];
}

extern "C" void kernel_launch(void* const* d_in, const int* in_sizes, int n_in,
                              void* d_out, int out_size, void* d_ws, size_t ws_size,
                              hipStream_t stream) {
  (void)in_sizes; (void)n_in; (void)out_size; (void)ws_size;
  const float* h     = (const float*)d_in[0];
  const int*   edges = (const int*)d_in[1];
  const float* fcw   = (const float*)d_in[2];
  const float* al    = (const float*)d_in[3];
  const float* ar    = (const float*)d_in[4];
  const float* w1    = (const float*)d_in[5];
  const float* b1    = (const float*)d_in[6];
  const float* w2    = (const float*)d_in[7];
  const float* pw    = (const float*)d_in[8];
  const float* pb    = (const float*)d_in[9];
  float* out = (float*)d_out;

  char* ws = (char*)d_ws;
  size_t off = 0;
  auto alloc = [&](size_t bytes) -> void* {
    void* p = ws + off;
    off = (off + bytes + 255) & ~(size_t)255;
    return p;
  };
  unsigned short* featb = (unsigned short*)alloc((size_t)N_NODES * HD * 2);
  unsigned short* zb    = (unsigned short*)alloc((size_t)N_NODES * HD * 2);
  unsigned short* fcwT  = (unsigned short*)alloc((size_t)N_META * HD * IN_DIM * 2);
  unsigned short* w1T   = (unsigned short*)alloc((size_t)HD * HD * 2);
  float* el = (float*)alloc((size_t)N_NODES * HEADS * 4);
  float* er = (float*)alloc((size_t)N_NODES * HEADS * 4);
  int* bcnt  = (int*)alloc((size_t)(N_META * NBKT + 1) * 4);
  int* bbase = (int*)alloc((size_t)(N_META * NBKT + 1) * 4);
  int* gcur  = (int*)alloc((size_t)N_META * NBKT * 4);
  int* offs  = (int*)alloc((size_t)(N_META * N_NODES + 1) * 4);
  unsigned int* bktbuf = (unsigned int*)alloc((size_t)N_META * N_EDGES * 4);
  int* csr   = (int*)alloc((size_t)N_META * N_EDGES * 4);
  float* wnode = (float*)alloc((size_t)N_NODES * 4);
  // numden block: num[3*128] | den[3]
  float* numden = (float*)alloc((N_META * HD + N_META) * 4);
  float* num = numden;
  float* den = numden + N_META * HD;

  hipMemsetAsync(numden, 0, (N_META * HD + N_META) * 4, stream);
  hipMemsetAsync(bcnt, 0, (size_t)(N_META * NBKT + 1) * 4, stream);

  prep_kernel<<<(N_META * IN_DIM * HD + HD * HD + 255) / 256, 256, 0, stream>>>(
      fcw, w1, fcwT, w1T);

  dim3 egrid((N_EDGES + TILE_E - 1) / TILE_E, N_META);
  bhist_kernel<<<egrid, 256, 0, stream>>>(edges, bcnt);
  bscan_kernel<<<1, 1024, 0, stream>>>(bcnt, bbase, gcur);
  bin_kernel<<<egrid, 256, 0, stream>>>(edges, gcur, bktbuf);
  dim3 sgrid(NBKT, N_META);
  csr_sort_kernel<<<sgrid, 256, 0, stream>>>(bbase, bktbuf, offs, csr);

  dim3 ggrid((N_NODES + 63) / 64);
  for (int m = 0; m < N_META; ++m) {
    gemm_feat_mfma<<<ggrid, 256, 0, stream>>>(
        h, fcwT + (size_t)m * HD * IN_DIM, al + m * HD, ar + m * HD,
        featb, el, er, N_NODES);
    aggregate_kernel<<<(N_NODES + 3) / 4, 256, 0, stream>>>(
        offs + m * N_NODES, csr, (const unsigned int*)featb, el, er,
        (unsigned int*)zb);
    w_gemm_mfma<<<ggrid, 256, 0, stream>>>(zb, w1T, b1, w2, wnode, N_NODES);
    fused_acc_kernel<<<256, 128, 0, stream>>>(
        zb, wnode, num + m * HD, den + m, N_NODES);
  }
  final_kernel<<<1, 64, 0, stream>>>(num, den, pw, pb, out);
}

// Round 7
// 529.972 us; speedup vs baseline: 1.5965x; 1.0946x over previous
//
#include <hip/hip_runtime.h>

#define N_NODES 50000
#define N_EDGES 800000
#define N_META 3
#define IN_DIM 256
#define HD 128
#define HEADS 8
#define HID 16
#define OUT_DIM 8
#define NBKT 196          // ceil(50000/256) coarse buckets (256 nodes each)
#define TILE_E 4096       // edges per bin/bhist block

using bf16x8 = __attribute__((ext_vector_type(8))) short;
using f32x4  = __attribute__((ext_vector_type(4))) float;

__device__ __forceinline__ float bf2f(unsigned short u) {
  union { unsigned int i; float f; } x; x.i = ((unsigned int)u) << 16; return x.f;
}
__device__ __forceinline__ unsigned short f2bf(float f) {
  union { float f; unsigned int i; } x; x.f = f;
  unsigned int r = x.i + 0x7fffu + ((x.i >> 16) & 1u);
  return (unsigned short)(r >> 16);
}

// ---------------- prep: fcw -> fcwT bf16 [M][128][256]; w1 -> w1T bf16 [128][128]
__global__ __launch_bounds__(256)
void prep_kernel(const float* __restrict__ fcw, const float* __restrict__ w1,
                 unsigned short* __restrict__ fcwT, unsigned short* __restrict__ w1T) {
  int i = blockIdx.x * 256 + threadIdx.x;
  const int NFC = N_META * IN_DIM * HD;
  if (i < NFC) {
    int p = i / (IN_DIM * HD);
    int rem = i - p * (IN_DIM * HD);
    int k = rem / HD, n = rem - k * HD;
    fcwT[(size_t)p * HD * IN_DIM + n * IN_DIM + k] = f2bf(fcw[i]);
  } else if (i < NFC + HD * HD) {
    int j = i - NFC;
    int k = j / HD, n = j - k * HD;
    w1T[n * HD + k] = f2bf(w1[j]);
  }
}

// ------- MFMA GEMM: featb = bf16(h @ fc_w[m]); fused el/er epilogue -----------
__global__ __launch_bounds__(256)
void gemm_feat_mfma(const float* __restrict__ A,            // h [N,256] f32
                    const unsigned short* __restrict__ BT,  // fcwT [128][256] bf16
                    const float* __restrict__ AL,           // attn_l[m] [128]
                    const float* __restrict__ AR,           // attn_r[m] [128]
                    unsigned short* __restrict__ Cb,        // featb [N,128] bf16
                    float* __restrict__ el, float* __restrict__ er,
                    int nrows) {
  __shared__ unsigned short As[64 * 40];
  __shared__ unsigned short Bs[128 * 40];
  int tid = threadIdx.x;
  int w = tid >> 6, l = tid & 63, q = l >> 4, s = l & 15;
  int row0 = blockIdx.x * 64;
  f32x4 acc[8] = {};
  for (int k0 = 0; k0 < IN_DIM; k0 += 32) {
    {
      int r = tid >> 2, c = (tid & 3) * 8;
      int gr = row0 + r;
      float4 a0, a1;
      if (gr < nrows) {
        a0 = *(const float4*)(A + (size_t)gr * IN_DIM + k0 + c);
        a1 = *(const float4*)(A + (size_t)gr * IN_DIM + k0 + c + 4);
      } else {
        a0 = make_float4(0.f, 0.f, 0.f, 0.f); a1 = a0;
      }
      ushort4 u0, u1;
      u0.x = f2bf(a0.x); u0.y = f2bf(a0.y); u0.z = f2bf(a0.z); u0.w = f2bf(a0.w);
      u1.x = f2bf(a1.x); u1.y = f2bf(a1.y); u1.z = f2bf(a1.z); u1.w = f2bf(a1.w);
      *(ushort4*)&As[r * 40 + c]     = u0;
      *(ushort4*)&As[r * 40 + c + 4] = u1;
    }
    {
      int n = tid >> 1, c = (tid & 1) * 16;
      uint4 b0 = *(const uint4*)(BT + (size_t)n * IN_DIM + k0 + c);
      uint4 b1 = *(const uint4*)(BT + (size_t)n * IN_DIM + k0 + c + 8);
      *(uint4*)&Bs[n * 40 + c]     = b0;
      *(uint4*)&Bs[n * 40 + c + 8] = b1;
    }
    __syncthreads();
    bf16x8 af = *(bf16x8*)&As[(w * 16 + s) * 40 + q * 8];
    #pragma unroll
    for (int f = 0; f < 8; ++f) {
      bf16x8 bf = *(bf16x8*)&Bs[(f * 16 + s) * 40 + q * 8];
      acc[f] = __builtin_amdgcn_mfma_f32_16x16x32_bf16(af, bf, acc[f], 0, 0, 0);
    }
    __syncthreads();
  }
  // epilogue: store bf16 feat + fused el/er (head == col-frag f, dim == lane s)
  #pragma unroll
  for (int f = 0; f < 8; ++f) {
    float alv = AL[f * 16 + s], arv = AR[f * 16 + s];
    #pragma unroll
    for (int r = 0; r < 4; ++r) {
      int gr = row0 + w * 16 + q * 4 + r;
      if (gr < nrows) Cb[(size_t)gr * HD + f * 16 + s] = f2bf(acc[f][r]);
      float pl = acc[f][r] * alv, pr = acc[f][r] * arv;
      pl += __shfl_xor(pl, 1); pr += __shfl_xor(pr, 1);
      pl += __shfl_xor(pl, 2); pr += __shfl_xor(pr, 2);
      pl += __shfl_xor(pl, 4); pr += __shfl_xor(pr, 4);
      pl += __shfl_xor(pl, 8); pr += __shfl_xor(pr, 8);
      if (s == 0 && gr < nrows) {
        el[gr * HEADS + f] = pl;
        er[gr * HEADS + f] = pr;
      }
    }
  }
}

// ---------------- coarse-bucket histogram (LDS, then 196 atomics/block) -------
__global__ __launch_bounds__(256)
void bhist_kernel(const int* __restrict__ edges, int* __restrict__ bcnt) {
  __shared__ int lh[NBKT];
  int p = blockIdx.y;
  int e0 = blockIdx.x * TILE_E;
  int t = threadIdx.x;
  const int* dst = edges + (size_t)p * 2 * N_EDGES + N_EDGES;
  for (int i = t; i < NBKT; i += 256) lh[i] = 0;
  __syncthreads();
  for (int i = t; i < TILE_E; i += 256) {
    int e = e0 + i;
    if (e < N_EDGES) atomicAdd(&lh[dst[e] >> 8], 1);
  }
  __syncthreads();
  for (int i = t; i < NBKT; i += 256)
    if (lh[i]) atomicAdd(&bcnt[p * NBKT + i], lh[i]);
}

// ---------------- scan 588 bucket counts -> bucket bases + bin cursors -------
__global__ __launch_bounds__(1024)
void bscan_kernel(const int* __restrict__ bcnt, int* __restrict__ bbase,
                  int* __restrict__ gcur) {
  __shared__ int wsum[16];
  const int n = N_META * NBKT;
  int tid = threadIdx.x, lane = tid & 63, wid = tid >> 6;
  int v = (tid < n) ? bcnt[tid] : 0;
  int s = v;
  #pragma unroll
  for (int d = 1; d < 64; d <<= 1) {
    int t = __shfl_up(s, d);
    if (lane >= d) s += t;
  }
  if (lane == 63) wsum[wid] = s;
  __syncthreads();
  if (wid == 0 && lane < 16) {
    int x = wsum[lane];
    #pragma unroll
    for (int d = 1; d < 16; d <<= 1) {
      int t = __shfl_up(x, d);
      if (lane >= d) x += t;
    }
    wsum[lane] = x;
  }
  __syncthreads();
  int woff = (wid == 0) ? 0 : wsum[wid - 1];
  if (tid < n) {
    int excl = woff + s - v;
    bbase[tid] = excl;
    gcur[tid] = excl;
  }
  if (tid == 0) bbase[n] = wsum[15];
}

// ---------------- Pass A: bin edges into coarse buckets (append runs) ---------
// record = (dst&255)<<16 | src  (src < 50000 < 2^16)
__global__ __launch_bounds__(256)
void bin_kernel(const int* __restrict__ edges, int* __restrict__ gcur,
                unsigned int* __restrict__ bktbuf) {
  __shared__ int hist[NBKT];
  __shared__ int gbase[NBKT];
  __shared__ int fill[NBKT];
  int p = blockIdx.y;
  int e0 = blockIdx.x * TILE_E;
  int t = threadIdx.x;
  const int* src = edges + (size_t)p * 2 * N_EDGES;
  const int* dst = src + N_EDGES;
  for (int i = t; i < NBKT; i += 256) { hist[i] = 0; fill[i] = 0; }
  __syncthreads();
  for (int i = t; i < TILE_E; i += 256) {
    int e = e0 + i;
    if (e < N_EDGES) atomicAdd(&hist[dst[e] >> 8], 1);
  }
  __syncthreads();
  for (int i = t; i < NBKT; i += 256)
    gbase[i] = hist[i] ? atomicAdd(&gcur[p * NBKT + i], hist[i]) : 0;
  __syncthreads();
  for (int i = t; i < TILE_E; i += 256) {
    int e = e0 + i;
    if (e < N_EDGES) {
      int d = dst[e];
      int b = d >> 8;
      int r = atomicAdd(&fill[b], 1);
      bktbuf[gbase[b] + r] = ((unsigned int)(d & 255) << 16) | (unsigned int)src[e];
    }
  }
}

// ---- Pass B: per bucket: LDS hist+scan -> offs (coalesced) + exact scatter ---
__global__ __launch_bounds__(256)
void csr_sort_kernel(const int* __restrict__ bbase,
                     const unsigned int* __restrict__ bktbuf,
                     int* __restrict__ offs, int* __restrict__ csr) {
  __shared__ int lh[256];
  __shared__ int cur[256];
  __shared__ int wsum[4];
  int p = blockIdx.y, b = blockIdx.x, t = threadIdx.x;
  int lane = t & 63, wid = t >> 6;
  int idx = p * NBKT + b;
  int S = bbase[idx], E = bbase[idx + 1];
  int node0 = b * 256;
  int nn = min(256, N_NODES - node0);
  lh[t] = 0;
  __syncthreads();
  for (int i = S + t; i < E; i += 256) atomicAdd(&lh[bktbuf[i] >> 16], 1);
  __syncthreads();
  int v = lh[t];
  int s = v;
  #pragma unroll
  for (int d = 1; d < 64; d <<= 1) {
    int x = __shfl_up(s, d);
    if (lane >= d) s += x;
  }
  if (lane == 63) wsum[wid] = s;
  __syncthreads();
  int woff = 0;
  #pragma unroll
  for (int k = 0; k < 4; ++k) if (k < wid) woff += wsum[k];
  int excl = S + woff + s - v;
  if (t < nn) offs[p * N_NODES + node0 + t] = excl;
  cur[t] = excl;
  if (p == N_META - 1 && b == NBKT - 1 && t == 0)
    offs[N_META * N_NODES] = E;
  __syncthreads();
  for (int i = S + t; i < E; i += 256) {
    unsigned int rec = bktbuf[i];
    int pos = atomicAdd(&cur[rec >> 16], 1);
    csr[pos] = (int)(rec & 0xffffu);
  }
}

// ---------------- GAT aggregation (no max pass, bf16 gather, x4 unroll) -------
__global__ __launch_bounds__(256)
void aggregate_kernel(const int* __restrict__ offs, const int* __restrict__ csr,
                      const unsigned int* __restrict__ featb_u,  // [N][64] 2xbf16
                      const float* __restrict__ el, const float* __restrict__ er,
                      unsigned int* __restrict__ z_u) {           // [N][64] 2xbf16
  int node = blockIdx.x * 4 + (threadIdx.x >> 6);
  if (node >= N_NODES) return;
  int lane = threadIdx.x & 63;
  int hh = lane >> 3;
  int beg = offs[node], end = offs[node + 1];
  float erh = er[node * HEADS + hh];
  float ssum = 0.f, a0 = 0.f, a1 = 0.f;
  int i = beg;
  for (; i + 3 < end; i += 4) {
    int s0 = csr[i], s1 = csr[i + 1], s2 = csr[i + 2], s3 = csr[i + 3];
    float e0 = el[s0 * HEADS + hh] + erh;
    float e1 = el[s1 * HEADS + hh] + erh;
    float e2 = el[s2 * HEADS + hh] + erh;
    float e3 = el[s3 * HEADS + hh] + erh;
    unsigned int v0 = featb_u[(size_t)s0 * 64 + lane];
    unsigned int v1 = featb_u[(size_t)s1 * 64 + lane];
    unsigned int v2 = featb_u[(size_t)s2 * 64 + lane];
    unsigned int v3 = featb_u[(size_t)s3 * 64 + lane];
    e0 = e0 > 0.f ? e0 : 0.2f * e0;
    e1 = e1 > 0.f ? e1 : 0.2f * e1;
    e2 = e2 > 0.f ? e2 : 0.2f * e2;
    e3 = e3 > 0.f ? e3 : 0.2f * e3;
    float w0 = __expf(e0), w1 = __expf(e1), w2 = __expf(e2), w3 = __expf(e3);
    ssum += (w0 + w1) + (w2 + w3);
    a0 += w0 * __uint_as_float(v0 << 16) + w1 * __uint_as_float(v1 << 16)
        + w2 * __uint_as_float(v2 << 16) + w3 * __uint_as_float(v3 << 16);
    a1 += w0 * __uint_as_float(v0 & 0xffff0000u) + w1 * __uint_as_float(v1 & 0xffff0000u)
        + w2 * __uint_as_float(v2 & 0xffff0000u) + w3 * __uint_as_float(v3 & 0xffff0000u);
  }
  for (; i < end; ++i) {
    int s0 = csr[i];
    float e0 = el[s0 * HEADS + hh] + erh;
    unsigned int v0 = featb_u[(size_t)s0 * 64 + lane];
    e0 = e0 > 0.f ? e0 : 0.2f * e0;
    float w0 = __expf(e0);
    ssum += w0;
    a0 += w0 * __uint_as_float(v0 << 16);
    a1 += w0 * __uint_as_float(v0 & 0xffff0000u);
  }
  float inv = (end > beg) ? 1.f / ssum : 0.f;
  a0 *= inv; a1 *= inv;
  a0 = a0 > 0.f ? a0 : expm1f(a0);
  a1 = a1 > 0.f ? a1 : expm1f(a1);
  unsigned int packed = (unsigned int)f2bf(a0) | ((unsigned int)f2bf(a1) << 16);
  z_u[(size_t)node * 64 + lane] = packed;
}

// ------ MFMA GEMM + tanh/w2 + fused softmax-over-nodes accumulation -----------
// |w| <= ~1 (0.05-scale weights, tanh in (-1,1)): exp never overflows; softmax
// is shift-invariant so skipping the global max pass is exact.
__global__ __launch_bounds__(256)
void w_gemm_mfma(const unsigned short* __restrict__ Zb,    // [N,128] bf16
                 const unsigned short* __restrict__ BT,    // w1T [128][128] bf16
                 const float* __restrict__ B1, const float* __restrict__ W2,
                 float* __restrict__ num, float* __restrict__ den,
                 int nrows) {
  __shared__ unsigned short As[64 * 40];
  __shared__ unsigned short Bs[128 * 40];
  __shared__ float wrow[64];
  __shared__ float part[4][64][2];
  __shared__ float dpart[4];
  int tid = threadIdx.x;
  int w = tid >> 6, l = tid & 63, q = l >> 4, s = l & 15;
  int row0 = blockIdx.x * 64;
  f32x4 acc[8] = {};
  for (int k0 = 0; k0 < HD; k0 += 32) {
    {
      int r = tid >> 2, c = (tid & 3) * 8;
      int gr = row0 + r;
      uint4 a0 = make_uint4(0, 0, 0, 0);
      if (gr < nrows) a0 = *(const uint4*)(Zb + (size_t)gr * HD + k0 + c);
      *(uint4*)&As[r * 40 + c] = a0;
    }
    {
      int n = tid >> 1, c = (tid & 1) * 16;
      uint4 b0 = *(const uint4*)(BT + (size_t)n * HD + k0 + c);
      uint4 b1 = *(const uint4*)(BT + (size_t)n * HD + k0 + c + 8);
      *(uint4*)&Bs[n * 40 + c]     = b0;
      *(uint4*)&Bs[n * 40 + c + 8] = b1;
    }
    __syncthreads();
    bf16x8 af = *(bf16x8*)&As[(w * 16 + s) * 40 + q * 8];
    #pragma unroll
    for (int f = 0; f < 8; ++f) {
      bf16x8 bf = *(bf16x8*)&Bs[(f * 16 + s) * 40 + q * 8];
      acc[f] = __builtin_amdgcn_mfma_f32_16x16x32_bf16(af, bf, acc[f], 0, 0, 0);
    }
    __syncthreads();
  }
  float b1v[8], w2v[8];
  #pragma unroll
  for (int f = 0; f < 8; ++f) { b1v[f] = B1[f * 16 + s]; w2v[f] = W2[f * 16 + s]; }
  #pragma unroll
  for (int r = 0; r < 4; ++r) {
    float p = 0.f;
    #pragma unroll
    for (int f = 0; f < 8; ++f) p += tanhf(acc[f][r] + b1v[f]) * w2v[f];
    p += __shfl_xor(p, 1); p += __shfl_xor(p, 2);
    p += __shfl_xor(p, 4); p += __shfl_xor(p, 8);
    if (s == 0) wrow[w * 16 + q * 4 + r] = p;
  }
  __syncthreads();
  // fused: num += exp(w[row]) * z[row][:], den += exp(w[row]);
  // this block's Zb rows are L2-hot (just staged above). lane = z uint col.
  const unsigned int* Zu = (const unsigned int*)Zb;
  float a0 = 0.f, a1 = 0.f, ld = 0.f;
  for (int r = w; r < 64; r += 4) {
    int gr = row0 + r;
    if (gr < nrows) {
      float e = __expf(wrow[r]);
      unsigned int v = Zu[(size_t)gr * 64 + l];
      a0 += e * __uint_as_float(v << 16);
      a1 += e * __uint_as_float(v & 0xffff0000u);
      if (l == 0) ld += e;
    }
  }
  part[w][l][0] = a0;
  part[w][l][1] = a1;
  if (l == 0) dpart[w] = ld;
  __syncthreads();
  if (w == 0) {
    float s0 = part[0][l][0] + part[1][l][0] + part[2][l][0] + part[3][l][0];
    float s1 = part[0][l][1] + part[1][l][1] + part[2][l][1] + part[3][l][1];
    atomicAdd(&num[2 * l], s0);
    atomicAdd(&num[2 * l + 1], s1);
    if (l == 0) atomicAdd(den, dpart[0] + dpart[1] + dpart[2] + dpart[3]);
  }
}

// ---------------- final ------------------------------------------------------
__global__ void final_kernel(const float* __restrict__ num, const float* __restrict__ den,
                             const float* __restrict__ PW, const float* __restrict__ PB,
                             float* __restrict__ out) {
  int t = threadIdx.x;
  if (t >= N_META * OUT_DIM) return;
  int m = t >> 3, o = t & 7;
  float inv = 1.0f / den[m];
  float s = 0.f;
  for (int k = 0; k < HD; ++k) s += num[m * HD + k] * PW[k * OUT_DIM + o];
  out[t] = s * inv + PB[o];
}

extern "C" void kernel_launch(void* const* d_in, const int* in_sizes, int n_in,
                              void* d_out, int out_size, void* d_ws, size_t ws_size,
                              hipStream_t stream) {
  (void)in_sizes; (void)n_in; (void)out_size; (void)ws_size;
  const float* h     = (const float*)d_in[0];
  const int*   edges = (const int*)d_in[1];
  const float* fcw   = (const float*)d_in[2];
  const float* al    = (const float*)d_in[3];
  const float* ar    = (const float*)d_in[4];
  const float* w1    = (const float*)d_in[5];
  const float* b1    = (const float*)d_in[6];
  const float* w2    = (const float*)d_in[7];
  const float* pw    = (const float*)d_in[8];
  const float* pb    = (const float*)d_in[9];
  float* out = (float*)d_out;

  char* ws = (char*)d_ws;
  size_t off = 0;
  auto alloc = [&](size_t bytes) -> void* {
    void* p = ws + off;
    off = (off + bytes + 255) & ~(size_t)255;
    return p;
  };
  unsigned short* featb = (unsigned short*)alloc((size_t)N_NODES * HD * 2);
  unsigned short* zb    = (unsigned short*)alloc((size_t)N_NODES * HD * 2);
  unsigned short* fcwT  = (unsigned short*)alloc((size_t)N_META * HD * IN_DIM * 2);
  unsigned short* w1T   = (unsigned short*)alloc((size_t)HD * HD * 2);
  float* el = (float*)alloc((size_t)N_NODES * HEADS * 4);
  float* er = (float*)alloc((size_t)N_NODES * HEADS * 4);
  int* bcnt  = (int*)alloc((size_t)(N_META * NBKT + 1) * 4);
  int* bbase = (int*)alloc((size_t)(N_META * NBKT + 1) * 4);
  int* gcur  = (int*)alloc((size_t)N_META * NBKT * 4);
  int* offs  = (int*)alloc((size_t)(N_META * N_NODES + 1) * 4);
  unsigned int* bktbuf = (unsigned int*)alloc((size_t)N_META * N_EDGES * 4);
  int* csr   = (int*)alloc((size_t)N_META * N_EDGES * 4);
  // numden block: num[3*128] | den[3]
  float* numden = (float*)alloc((N_META * HD + N_META) * 4);
  float* num = numden;
  float* den = numden + N_META * HD;

  hipMemsetAsync(numden, 0, (N_META * HD + N_META) * 4, stream);
  hipMemsetAsync(bcnt, 0, (size_t)(N_META * NBKT + 1) * 4, stream);

  prep_kernel<<<(N_META * IN_DIM * HD + HD * HD + 255) / 256, 256, 0, stream>>>(
      fcw, w1, fcwT, w1T);

  dim3 egrid((N_EDGES + TILE_E - 1) / TILE_E, N_META);
  bhist_kernel<<<egrid, 256, 0, stream>>>(edges, bcnt);
  bscan_kernel<<<1, 1024, 0, stream>>>(bcnt, bbase, gcur);
  bin_kernel<<<egrid, 256, 0, stream>>>(edges, gcur, bktbuf);
  dim3 sgrid(NBKT, N_META);
  csr_sort_kernel<<<sgrid, 256, 0, stream>>>(bbase, bktbuf, offs, csr);

  dim3 ggrid((N_NODES + 63) / 64);
  for (int m = 0; m < N_META; ++m) {
    gemm_feat_mfma<<<ggrid, 256, 0, stream>>>(
        h, fcwT + (size_t)m * HD * IN_DIM, al + m * HD, ar + m * HD,
        featb, el, er, N_NODES);
    aggregate_kernel<<<(N_NODES + 3) / 4, 256, 0, stream>>>(
        offs + m * N_NODES, csr, (const unsigned int*)featb, el, er,
        (unsigned int*)zb);
    w_gemm_mfma<<<ggrid, 256, 0, stream>>>(
        zb, w1T, b1, w2, num + m * HD, den + m, N_NODES);
  }
  final_kernel<<<1, 64, 0, stream>>>(num, den, pw, pb, out);
}

// Round 8
// 466.602 us; speedup vs baseline: 1.8133x; 1.1358x over previous
//
#include <hip/hip_runtime.h>

#define N_NODES 50000
#define N_EDGES 800000
#define N_META 3
#define IN_DIM 256
#define HD 128
#define HEADS 8
#define HID 16
#define OUT_DIM 8
#define NBKT 196          // ceil(50000/256) coarse buckets (256 nodes each)
#define TILE_E 4096       // edges per bin/bhist block
#define NUMPAD 2064       // per-meta padded accum: 128 cols * 16 floats + den

using bf16x8 = __attribute__((ext_vector_type(8))) short;
using f32x4  = __attribute__((ext_vector_type(4))) float;

__device__ __forceinline__ float bf2f(unsigned short u) {
  union { unsigned int i; float f; } x; x.i = ((unsigned int)u) << 16; return x.f;
}
__device__ __forceinline__ unsigned short f2bf(float f) {
  union { float f; unsigned int i; } x; x.f = f;
  unsigned int r = x.i + 0x7fffu + ((x.i >> 16) & 1u);
  return (unsigned short)(r >> 16);
}

// ---------------- prep: fcw -> fcwT bf16 [M][128][256]; w1 -> w1T bf16 [128][128]
__global__ __launch_bounds__(256)
void prep_kernel(const float* __restrict__ fcw, const float* __restrict__ w1,
                 unsigned short* __restrict__ fcwT, unsigned short* __restrict__ w1T) {
  int i = blockIdx.x * 256 + threadIdx.x;
  const int NFC = N_META * IN_DIM * HD;
  if (i < NFC) {
    int p = i / (IN_DIM * HD);
    int rem = i - p * (IN_DIM * HD);
    int k = rem / HD, n = rem - k * HD;
    fcwT[(size_t)p * HD * IN_DIM + n * IN_DIM + k] = f2bf(fcw[i]);
  } else if (i < NFC + HD * HD) {
    int j = i - NFC;
    int k = j / HD, n = j - k * HD;
    w1T[n * HD + k] = f2bf(w1[j]);
  }
}

// ------- MFMA GEMM: featb = bf16(h @ fc_w[m]); fused el/er epilogue -----------
__global__ __launch_bounds__(256)
void gemm_feat_mfma(const float* __restrict__ A,            // h [N,256] f32
                    const unsigned short* __restrict__ BT,  // fcwT [128][256] bf16
                    const float* __restrict__ AL,           // attn_l[m] [128]
                    const float* __restrict__ AR,           // attn_r[m] [128]
                    unsigned short* __restrict__ Cb,        // featb [N,128] bf16
                    float* __restrict__ el, float* __restrict__ er,
                    int nrows) {
  __shared__ unsigned short As[64 * 40];
  __shared__ unsigned short Bs[128 * 40];
  int tid = threadIdx.x;
  int w = tid >> 6, l = tid & 63, q = l >> 4, s = l & 15;
  int row0 = blockIdx.x * 64;
  f32x4 acc[8] = {};
  for (int k0 = 0; k0 < IN_DIM; k0 += 32) {
    {
      int r = tid >> 2, c = (tid & 3) * 8;
      int gr = row0 + r;
      float4 a0, a1;
      if (gr < nrows) {
        a0 = *(const float4*)(A + (size_t)gr * IN_DIM + k0 + c);
        a1 = *(const float4*)(A + (size_t)gr * IN_DIM + k0 + c + 4);
      } else {
        a0 = make_float4(0.f, 0.f, 0.f, 0.f); a1 = a0;
      }
      ushort4 u0, u1;
      u0.x = f2bf(a0.x); u0.y = f2bf(a0.y); u0.z = f2bf(a0.z); u0.w = f2bf(a0.w);
      u1.x = f2bf(a1.x); u1.y = f2bf(a1.y); u1.z = f2bf(a1.z); u1.w = f2bf(a1.w);
      *(ushort4*)&As[r * 40 + c]     = u0;
      *(ushort4*)&As[r * 40 + c + 4] = u1;
    }
    {
      int n = tid >> 1, c = (tid & 1) * 16;
      uint4 b0 = *(const uint4*)(BT + (size_t)n * IN_DIM + k0 + c);
      uint4 b1 = *(const uint4*)(BT + (size_t)n * IN_DIM + k0 + c + 8);
      *(uint4*)&Bs[n * 40 + c]     = b0;
      *(uint4*)&Bs[n * 40 + c + 8] = b1;
    }
    __syncthreads();
    bf16x8 af = *(bf16x8*)&As[(w * 16 + s) * 40 + q * 8];
    #pragma unroll
    for (int f = 0; f < 8; ++f) {
      bf16x8 bf = *(bf16x8*)&Bs[(f * 16 + s) * 40 + q * 8];
      acc[f] = __builtin_amdgcn_mfma_f32_16x16x32_bf16(af, bf, acc[f], 0, 0, 0);
    }
    __syncthreads();
  }
  // epilogue: store bf16 feat + fused el/er (head == col-frag f, dim == lane s)
  #pragma unroll
  for (int f = 0; f < 8; ++f) {
    float alv = AL[f * 16 + s], arv = AR[f * 16 + s];
    #pragma unroll
    for (int r = 0; r < 4; ++r) {
      int gr = row0 + w * 16 + q * 4 + r;
      if (gr < nrows) Cb[(size_t)gr * HD + f * 16 + s] = f2bf(acc[f][r]);
      float pl = acc[f][r] * alv, pr = acc[f][r] * arv;
      pl += __shfl_xor(pl, 1); pr += __shfl_xor(pr, 1);
      pl += __shfl_xor(pl, 2); pr += __shfl_xor(pr, 2);
      pl += __shfl_xor(pl, 4); pr += __shfl_xor(pr, 4);
      pl += __shfl_xor(pl, 8); pr += __shfl_xor(pr, 8);
      if (s == 0 && gr < nrows) {
        el[gr * HEADS + f] = pl;
        er[gr * HEADS + f] = pr;
      }
    }
  }
}

// ---------------- coarse-bucket histogram (LDS, then 196 atomics/block) -------
__global__ __launch_bounds__(256)
void bhist_kernel(const int* __restrict__ edges, int* __restrict__ bcnt) {
  __shared__ int lh[NBKT];
  int p = blockIdx.y;
  int e0 = blockIdx.x * TILE_E;
  int t = threadIdx.x;
  const int* dst = edges + (size_t)p * 2 * N_EDGES + N_EDGES;
  for (int i = t; i < NBKT; i += 256) lh[i] = 0;
  __syncthreads();
  for (int i = t; i < TILE_E; i += 256) {
    int e = e0 + i;
    if (e < N_EDGES) atomicAdd(&lh[dst[e] >> 8], 1);
  }
  __syncthreads();
  for (int i = t; i < NBKT; i += 256)
    if (lh[i]) atomicAdd(&bcnt[p * NBKT + i], lh[i]);
}

// ---------------- scan 588 bucket counts -> bucket bases + bin cursors -------
__global__ __launch_bounds__(1024)
void bscan_kernel(const int* __restrict__ bcnt, int* __restrict__ bbase,
                  int* __restrict__ gcur) {
  __shared__ int wsum[16];
  const int n = N_META * NBKT;
  int tid = threadIdx.x, lane = tid & 63, wid = tid >> 6;
  int v = (tid < n) ? bcnt[tid] : 0;
  int s = v;
  #pragma unroll
  for (int d = 1; d < 64; d <<= 1) {
    int t = __shfl_up(s, d);
    if (lane >= d) s += t;
  }
  if (lane == 63) wsum[wid] = s;
  __syncthreads();
  if (wid == 0 && lane < 16) {
    int x = wsum[lane];
    #pragma unroll
    for (int d = 1; d < 16; d <<= 1) {
      int t = __shfl_up(x, d);
      if (lane >= d) x += t;
    }
    wsum[lane] = x;
  }
  __syncthreads();
  int woff = (wid == 0) ? 0 : wsum[wid - 1];
  if (tid < n) {
    int excl = woff + s - v;
    bbase[tid] = excl;
    gcur[tid] = excl;
  }
  if (tid == 0) bbase[n] = wsum[15];
}

// ---------------- Pass A: bin edges into coarse buckets (append runs) ---------
// record = (dst&255)<<16 | src  (src < 50000 < 2^16)
__global__ __launch_bounds__(256)
void bin_kernel(const int* __restrict__ edges, int* __restrict__ gcur,
                unsigned int* __restrict__ bktbuf) {
  __shared__ int hist[NBKT];
  __shared__ int gbase[NBKT];
  __shared__ int fill[NBKT];
  int p = blockIdx.y;
  int e0 = blockIdx.x * TILE_E;
  int t = threadIdx.x;
  const int* src = edges + (size_t)p * 2 * N_EDGES;
  const int* dst = src + N_EDGES;
  for (int i = t; i < NBKT; i += 256) { hist[i] = 0; fill[i] = 0; }
  __syncthreads();
  for (int i = t; i < TILE_E; i += 256) {
    int e = e0 + i;
    if (e < N_EDGES) atomicAdd(&hist[dst[e] >> 8], 1);
  }
  __syncthreads();
  for (int i = t; i < NBKT; i += 256)
    gbase[i] = hist[i] ? atomicAdd(&gcur[p * NBKT + i], hist[i]) : 0;
  __syncthreads();
  for (int i = t; i < TILE_E; i += 256) {
    int e = e0 + i;
    if (e < N_EDGES) {
      int d = dst[e];
      int b = d >> 8;
      int r = atomicAdd(&fill[b], 1);
      bktbuf[gbase[b] + r] = ((unsigned int)(d & 255) << 16) | (unsigned int)src[e];
    }
  }
}

// ---- Pass B: per bucket: LDS hist+scan -> offs (coalesced) + exact scatter ---
__global__ __launch_bounds__(256)
void csr_sort_kernel(const int* __restrict__ bbase,
                     const unsigned int* __restrict__ bktbuf,
                     int* __restrict__ offs, int* __restrict__ csr) {
  __shared__ int lh[256];
  __shared__ int cur[256];
  __shared__ int wsum[4];
  int p = blockIdx.y, b = blockIdx.x, t = threadIdx.x;
  int lane = t & 63, wid = t >> 6;
  int idx = p * NBKT + b;
  int S = bbase[idx], E = bbase[idx + 1];
  int node0 = b * 256;
  int nn = min(256, N_NODES - node0);
  lh[t] = 0;
  __syncthreads();
  for (int i = S + t; i < E; i += 256) atomicAdd(&lh[bktbuf[i] >> 16], 1);
  __syncthreads();
  int v = lh[t];
  int s = v;
  #pragma unroll
  for (int d = 1; d < 64; d <<= 1) {
    int x = __shfl_up(s, d);
    if (lane >= d) s += x;
  }
  if (lane == 63) wsum[wid] = s;
  __syncthreads();
  int woff = 0;
  #pragma unroll
  for (int k = 0; k < 4; ++k) if (k < wid) woff += wsum[k];
  int excl = S + woff + s - v;
  if (t < nn) offs[p * N_NODES + node0 + t] = excl;
  cur[t] = excl;
  if (p == N_META - 1 && b == NBKT - 1 && t == 0)
    offs[N_META * N_NODES] = E;
  __syncthreads();
  for (int i = S + t; i < E; i += 256) {
    unsigned int rec = bktbuf[i];
    int pos = atomicAdd(&cur[rec >> 16], 1);
    csr[pos] = (int)(rec & 0xffffu);
  }
}

// ---------------- GAT aggregation (no max pass, bf16 gather, x4 unroll) -------
__global__ __launch_bounds__(256)
void aggregate_kernel(const int* __restrict__ offs, const int* __restrict__ csr,
                      const unsigned int* __restrict__ featb_u,  // [N][64] 2xbf16
                      const float* __restrict__ el, const float* __restrict__ er,
                      unsigned int* __restrict__ z_u) {           // [N][64] 2xbf16
  int node = blockIdx.x * 4 + (threadIdx.x >> 6);
  if (node >= N_NODES) return;
  int lane = threadIdx.x & 63;
  int hh = lane >> 3;
  int beg = offs[node], end = offs[node + 1];
  float erh = er[node * HEADS + hh];
  float ssum = 0.f, a0 = 0.f, a1 = 0.f;
  int i = beg;
  for (; i + 3 < end; i += 4) {
    int s0 = csr[i], s1 = csr[i + 1], s2 = csr[i + 2], s3 = csr[i + 3];
    float e0 = el[s0 * HEADS + hh] + erh;
    float e1 = el[s1 * HEADS + hh] + erh;
    float e2 = el[s2 * HEADS + hh] + erh;
    float e3 = el[s3 * HEADS + hh] + erh;
    unsigned int v0 = featb_u[(size_t)s0 * 64 + lane];
    unsigned int v1 = featb_u[(size_t)s1 * 64 + lane];
    unsigned int v2 = featb_u[(size_t)s2 * 64 + lane];
    unsigned int v3 = featb_u[(size_t)s3 * 64 + lane];
    e0 = e0 > 0.f ? e0 : 0.2f * e0;
    e1 = e1 > 0.f ? e1 : 0.2f * e1;
    e2 = e2 > 0.f ? e2 : 0.2f * e2;
    e3 = e3 > 0.f ? e3 : 0.2f * e3;
    float w0 = __expf(e0), w1 = __expf(e1), w2 = __expf(e2), w3 = __expf(e3);
    ssum += (w0 + w1) + (w2 + w3);
    a0 += w0 * __uint_as_float(v0 << 16) + w1 * __uint_as_float(v1 << 16)
        + w2 * __uint_as_float(v2 << 16) + w3 * __uint_as_float(v3 << 16);
    a1 += w0 * __uint_as_float(v0 & 0xffff0000u) + w1 * __uint_as_float(v1 & 0xffff0000u)
        + w2 * __uint_as_float(v2 & 0xffff0000u) + w3 * __uint_as_float(v3 & 0xffff0000u);
  }
  for (; i < end; ++i) {
    int s0 = csr[i];
    float e0 = el[s0 * HEADS + hh] + erh;
    unsigned int v0 = featb_u[(size_t)s0 * 64 + lane];
    e0 = e0 > 0.f ? e0 : 0.2f * e0;
    float w0 = __expf(e0);
    ssum += w0;
    a0 += w0 * __uint_as_float(v0 << 16);
    a1 += w0 * __uint_as_float(v0 & 0xffff0000u);
  }
  float inv = (end > beg) ? 1.f / ssum : 0.f;
  a0 *= inv; a1 *= inv;
  a0 = a0 > 0.f ? a0 : expm1f(a0);
  a1 = a1 > 0.f ? a1 : expm1f(a1);
  unsigned int packed = (unsigned int)f2bf(a0) | ((unsigned int)f2bf(a1) << 16);
  z_u[(size_t)node * 64 + lane] = packed;
}

// ------ MFMA GEMM (256 rows/block) + tanh/w2 + fused node-softmax accum -------
// numpad layout: col c at numpad[c*16] (one 64B line per column), den at [2048].
// |w| <= ~1 so unshifted exp is exact for softmax.
__global__ __launch_bounds__(256)
void w_gemm_mfma(const unsigned short* __restrict__ Zb,    // [N,128] bf16
                 const unsigned short* __restrict__ BT,    // w1T [128][128] bf16
                 const float* __restrict__ B1, const float* __restrict__ W2,
                 float* __restrict__ numpad, int nrows) {
  __shared__ unsigned short Bs[128 * 136];
  __shared__ unsigned short As[64 * 136];
  __shared__ float wrow[64];
  __shared__ float part[4][64][2];
  __shared__ float dpart[4];
  int tid = threadIdx.x;
  int w = tid >> 6, l = tid & 63, q = l >> 4, s = l & 15;
  // stage full w1T (128x128) once
  {
    int n = tid >> 1, c0 = (tid & 1) * 64;
    #pragma unroll
    for (int j = 0; j < 8; ++j)
      *(uint4*)&Bs[n * 136 + c0 + j * 8] = *(const uint4*)(BT + n * HD + c0 + j * 8);
  }
  float b1v[8], w2v[8];
  #pragma unroll
  for (int f = 0; f < 8; ++f) { b1v[f] = B1[f * 16 + s]; w2v[f] = W2[f * 16 + s]; }
  const unsigned int* Zu = (const unsigned int*)Zb;
  float a0 = 0.f, a1 = 0.f, ld = 0.f;
  for (int t = 0; t < 4; ++t) {
    int row0 = blockIdx.x * 256 + t * 64;
    __syncthreads();   // Bs visible (t=0); prev tile's wrow/As consumers done
    {
      int r = tid >> 2, c0 = (tid & 3) * 32;
      int gr = row0 + r;
      if (gr < nrows) {
        #pragma unroll
        for (int j = 0; j < 4; ++j)
          *(uint4*)&As[r * 136 + c0 + j * 8] =
              *(const uint4*)(Zb + (size_t)gr * HD + c0 + j * 8);
      } else {
        uint4 z = make_uint4(0, 0, 0, 0);
        #pragma unroll
        for (int j = 0; j < 4; ++j) *(uint4*)&As[r * 136 + c0 + j * 8] = z;
      }
    }
    __syncthreads();
    f32x4 acc[8] = {};
    #pragma unroll
    for (int kc = 0; kc < 4; ++kc) {
      bf16x8 af = *(bf16x8*)&As[(w * 16 + s) * 136 + kc * 32 + q * 8];
      #pragma unroll
      for (int f = 0; f < 8; ++f) {
        bf16x8 bf = *(bf16x8*)&Bs[(f * 16 + s) * 136 + kc * 32 + q * 8];
        acc[f] = __builtin_amdgcn_mfma_f32_16x16x32_bf16(af, bf, acc[f], 0, 0, 0);
      }
    }
    #pragma unroll
    for (int r = 0; r < 4; ++r) {
      float p = 0.f;
      #pragma unroll
      for (int f = 0; f < 8; ++f) p += tanhf(acc[f][r] + b1v[f]) * w2v[f];
      p += __shfl_xor(p, 1); p += __shfl_xor(p, 2);
      p += __shfl_xor(p, 4); p += __shfl_xor(p, 8);
      if (s == 0) wrow[w * 16 + q * 4 + r] = p;
    }
    __syncthreads();
    for (int r = w; r < 64; r += 4) {
      int gr = row0 + r;
      if (gr < nrows) {
        float e = __expf(wrow[r]);
        unsigned int v = Zu[(size_t)gr * 64 + l];
        a0 += e * __uint_as_float(v << 16);
        a1 += e * __uint_as_float(v & 0xffff0000u);
        if (l == 0) ld += e;
      }
    }
  }
  part[w][l][0] = a0;
  part[w][l][1] = a1;
  if (l == 0) dpart[w] = ld;
  __syncthreads();
  if (w == 0) {
    float s0 = part[0][l][0] + part[1][l][0] + part[2][l][0] + part[3][l][0];
    float s1 = part[0][l][1] + part[1][l][1] + part[2][l][1] + part[3][l][1];
    atomicAdd(&numpad[(2 * l) * 16], s0);
    atomicAdd(&numpad[(2 * l + 1) * 16], s1);
    if (l == 0)
      atomicAdd(&numpad[128 * 16], dpart[0] + dpart[1] + dpart[2] + dpart[3]);
  }
}

// ---------------- final ------------------------------------------------------
__global__ void final_kernel(const float* __restrict__ numpad,
                             const float* __restrict__ PW, const float* __restrict__ PB,
                             float* __restrict__ out) {
  int t = threadIdx.x;
  if (t >= N_META * OUT_DIM) return;
  int m = t >> 3, o = t & 7;
  const float* np = numpad + m * NUMPAD;
  float inv = 1.0f / np[128 * 16];
  float s = 0.f;
  for (int k = 0; k < HD; ++k) s += np[k * 16] * PW[k * OUT_DIM + o];
  out[t] = s * inv + PB[o];
}

extern "C" void kernel_launch(void* const* d_in, const int* in_sizes, int n_in,
                              void* d_out, int out_size, void* d_ws, size_t ws_size,
                              hipStream_t stream) {
  (void)in_sizes; (void)n_in; (void)out_size; (void)ws_size;
  const float* h     = (const float*)d_in[0];
  const int*   edges = (const int*)d_in[1];
  const float* fcw   = (const float*)d_in[2];
  const float* al    = (const float*)d_in[3];
  const float* ar    = (const float*)d_in[4];
  const float* w1    = (const float*)d_in[5];
  const float* b1    = (const float*)d_in[6];
  const float* w2    = (const float*)d_in[7];
  const float* pw    = (const float*)d_in[8];
  const float* pb    = (const float*)d_in[9];
  float* out = (float*)d_out;

  char* ws = (char*)d_ws;
  size_t off = 0;
  auto alloc = [&](size_t bytes) -> void* {
    void* p = ws + off;
    off = (off + bytes + 255) & ~(size_t)255;
    return p;
  };
  unsigned short* featb = (unsigned short*)alloc((size_t)N_NODES * HD * 2);
  unsigned short* zb    = (unsigned short*)alloc((size_t)N_NODES * HD * 2);
  unsigned short* fcwT  = (unsigned short*)alloc((size_t)N_META * HD * IN_DIM * 2);
  unsigned short* w1T   = (unsigned short*)alloc((size_t)HD * HD * 2);
  float* el = (float*)alloc((size_t)N_NODES * HEADS * 4);
  float* er = (float*)alloc((size_t)N_NODES * HEADS * 4);
  int* bcnt  = (int*)alloc((size_t)(N_META * NBKT + 1) * 4);
  int* bbase = (int*)alloc((size_t)(N_META * NBKT + 1) * 4);
  int* gcur  = (int*)alloc((size_t)N_META * NBKT * 4);
  int* offs  = (int*)alloc((size_t)(N_META * N_NODES + 1) * 4);
  unsigned int* bktbuf = (unsigned int*)alloc((size_t)N_META * N_EDGES * 4);
  int* csr   = (int*)alloc((size_t)N_META * N_EDGES * 4);
  float* numpad = (float*)alloc((size_t)N_META * NUMPAD * 4);

  hipMemsetAsync(numpad, 0, (size_t)N_META * NUMPAD * 4, stream);
  hipMemsetAsync(bcnt, 0, (size_t)(N_META * NBKT + 1) * 4, stream);

  prep_kernel<<<(N_META * IN_DIM * HD + HD * HD + 255) / 256, 256, 0, stream>>>(
      fcw, w1, fcwT, w1T);

  dim3 egrid((N_EDGES + TILE_E - 1) / TILE_E, N_META);
  bhist_kernel<<<egrid, 256, 0, stream>>>(edges, bcnt);
  bscan_kernel<<<1, 1024, 0, stream>>>(bcnt, bbase, gcur);
  bin_kernel<<<egrid, 256, 0, stream>>>(edges, gcur, bktbuf);
  dim3 sgrid(NBKT, N_META);
  csr_sort_kernel<<<sgrid, 256, 0, stream>>>(bbase, bktbuf, offs, csr);

  dim3 ggrid((N_NODES + 63) / 64);
  dim3 wgrid((N_NODES + 255) / 256);
  for (int m = 0; m < N_META; ++m) {
    gemm_feat_mfma<<<ggrid, 256, 0, stream>>>(
        h, fcwT + (size_t)m * HD * IN_DIM, al + m * HD, ar + m * HD,
        featb, el, er, N_NODES);
    aggregate_kernel<<<(N_NODES + 3) / 4, 256, 0, stream>>>(
        offs + m * N_NODES, csr, (const unsigned int*)featb, el, er,
        (unsigned int*)zb);
    w_gemm_mfma<<<wgrid, 256, 0, stream>>>(
        zb, w1T, b1, w2, numpad + (size_t)m * NUMPAD, N_NODES);
  }
  final_kernel<<<1, 64, 0, stream>>>(numpad, pw, pb, out);
}